// Round 16
// baseline (452.454 us; speedup 1.0000x reference)
//
#include <hip/hip_runtime.h>
#include <math.h>

#define MBS   64
#define QLENS 20
#define EMBS  32
#define QVSS  128
#define ANSS  10
#define CHS   24
#define NOBJS 64
#define GS    256

typedef __attribute__((ext_vector_type(8))) short short8;
typedef __attribute__((ext_vector_type(4))) float f32x4;
typedef __attribute__((ext_vector_type(16))) float f32x16;

__device__ __forceinline__ unsigned short f2bf(float f) {
  unsigned u = __float_as_uint(f);
  u += 0x7fffu + ((u >> 16) & 1u);
  return (unsigned short)(u >> 16);
}
__device__ __forceinline__ float sigm(float x) { return 1.0f / (1.0f + expf(-x)); }

// ---------------- prep: g-weights f32->bf16 [48][2][256][8] + g1w transpose ----------------
// wbf buffer is PADDED to 52 chunks (last 4 uninitialized): rel_k's B-prefetch reads
// pc up to 51 without a clamp; those values never reach an MFMA.
__global__ __launch_bounds__(256) void prep_k(const float* __restrict__ g2w,
                                              const float* __restrict__ g3w,
                                              const float* __restrict__ g4w,
                                              unsigned short* __restrict__ wbf,
                                              const float* __restrict__ g1w,
                                              float* __restrict__ g1wT) {
  int bidx = blockIdx.x;
  if (bidx < 768) {
    int idx = bidx * 256 + threadIdx.x;              // 3*65536
    int l = idx >> 16, r = idx & 65535;
    int kt = r >> 12;
    int rem = r & 4095;
    int kh = rem >> 11;
    int n = (rem >> 3) & 255;
    int e = rem & 7;
    const float* src = (l == 0) ? g2w : ((l == 1) ? g3w : g4w);
    wbf[idx] = f2bf(src[n * 256 + kt * 16 + kh * 8 + e]);
  } else {
    int idx = (bidx - 768) * 256 + threadIdx.x;      // 180*256
    int f = idx >> 8, n = idx & 255;
    g1wT[f * 256 + n] = g1w[n * 180 + f];
  }
}

// ---------------- fused embed+proj + sequential LSTM, one block per batch ----------------
__global__ __launch_bounds__(512) void lstm_k(const int* __restrict__ question,
                                              const float* __restrict__ emb,
                                              const float* __restrict__ wih,
                                              const float* __restrict__ bih,
                                              const float* __restrict__ bhh,
                                              const float* __restrict__ whh,
                                              float* __restrict__ qvec) {
  int b = blockIdx.x;
  int gt = threadIdx.x;                               // 0..511
  __shared__ float h[QVSS];
  __shared__ float gates[4 * QVSS];
  __shared__ int toks[QLENS];
  float w[QVSS];
#pragma unroll
  for (int k = 0; k < QVSS; ++k) w[k] = whh[gt * QVSS + k];
  float wi[EMBS];
#pragma unroll
  for (int k = 0; k < EMBS; ++k) wi[k] = wih[gt * EMBS + k];
  float bb = bih[gt] + bhh[gt];
  if (gt < QLENS) toks[gt] = question[b * QLENS + gt];
  float c = 0.0f;
  if (gt < QVSS) h[gt] = 0.0f;
  __syncthreads();
  float xp[QLENS];
#pragma unroll
  for (int t = 0; t < QLENS; ++t) {
    const float* e = emb + toks[t] * EMBS;
    float a = bb;
#pragma unroll
    for (int k = 0; k < EMBS; ++k) a += wi[k] * e[k];
    xp[t] = a;
  }
  for (int t = 0; t < QLENS; ++t) {
    float acc = xp[t];
#pragma unroll
    for (int k4 = 0; k4 < QVSS / 4; ++k4) {           // float4 LDS reads
      float4 hv = *reinterpret_cast<const float4*>(&h[k4 * 4]);
      acc += w[k4 * 4 + 0] * hv.x + w[k4 * 4 + 1] * hv.y
           + w[k4 * 4 + 2] * hv.z + w[k4 * 4 + 3] * hv.w;
    }
    gates[gt] = acc;
    __syncthreads();
    if (gt < QVSS) {
      float ig = gates[gt];
      float fg = gates[QVSS + gt];
      float gg = gates[2 * QVSS + gt];
      float og = gates[3 * QVSS + gt];
      c = sigm(fg) * c + sigm(ig) * tanhf(gg);
      h[gt] = sigm(og) * tanhf(c);
    }
    __syncthreads();
  }
  if (gt < QVSS) qvec[b * QVSS + gt] = h[gt];
}

// ---------------- direct conv (stride2 pad1 3x3), 16 outputs/thread (4 co x 4 ow) ----------------
// Input loads (2 float4 + 1 edge scalar) shared across the co-quad: 3 loads feed 48 FMA.
template <int CIN, int H>
__global__ __launch_bounds__(256) void conv_k(const float* __restrict__ x,
                                              const float* __restrict__ w,
                                              const float* __restrict__ bias,
                                              float* __restrict__ y) {
  const int OH = H / 2, GW = OH / 4, CP = CHS / 4;
  __shared__ float4 swp[CHS * CIN * 3];
  __shared__ float sb[CHS];
  for (int i = threadIdx.x; i < CHS * CIN * 3; i += 256) {
    int kh = i % 3, ci = (i / 3) % CIN, co = i / (3 * CIN);
    const float* wp = w + (co * CIN + ci) * 9 + kh * 3;
    swp[i] = make_float4(wp[0], wp[1], wp[2], 0.0f);
  }
  if (threadIdx.x < CHS) sb[threadIdx.x] = bias[threadIdx.x];
  __syncthreads();
  int idx = blockIdx.x * 256 + threadIdx.x;           // 64*6*OH*GW, exact grid
  int g = idx % GW;
  int oh = (idx / GW) % OH;
  int cp = (idx / (GW * OH)) % CP;
  int b  = idx / (CP * OH * GW);
  int co0 = cp * 4;
  float acc[4][4];
#pragma unroll
  for (int q = 0; q < 4; ++q) {
    float bq = sb[co0 + q];
#pragma unroll
    for (int o = 0; o < 4; ++o) acc[q][o] = bq;
  }
  const float* xb = x + b * CIN * H * H;
  bool left = (g > 0);
#pragma unroll
  for (int kh = 0; kh < 3; ++kh) {
    int ih = oh * 2 - 1 + kh;
    if (ih < 0 || ih >= H) continue;
    for (int ci = 0; ci < CIN; ++ci) {
      const float* row = xb + (ci * H + ih) * H + 8 * g;
      float4 v1 = *(const float4*)(row);
      float4 v2 = *(const float4*)(row + 4);
      float am1 = left ? row[-1] : 0.0f;              // zero-pad at iw = -1
      // 9 input taps shared by 4 output channels
      float i0a = am1,  i0b = v1.x, i0c = v1.y;       // ow0: taps -1,0,1
      float i1a = v1.y, i1b = v1.z, i1c = v1.w;       // ow1: taps 1,2,3
      float i2a = v1.w, i2b = v2.x, i2c = v2.y;       // ow2: taps 3,4,5
      float i3a = v2.y, i3b = v2.z, i3c = v2.w;       // ow3: taps 5,6,7
#pragma unroll
      for (int q = 0; q < 4; ++q) {
        float4 wv = swp[(co0 + q) * CIN * 3 + ci * 3 + kh];
        acc[q][0] = fmaf(wv.x, i0a, acc[q][0]); acc[q][0] = fmaf(wv.y, i0b, acc[q][0]); acc[q][0] = fmaf(wv.z, i0c, acc[q][0]);
        acc[q][1] = fmaf(wv.x, i1a, acc[q][1]); acc[q][1] = fmaf(wv.y, i1b, acc[q][1]); acc[q][1] = fmaf(wv.z, i1c, acc[q][1]);
        acc[q][2] = fmaf(wv.x, i2a, acc[q][2]); acc[q][2] = fmaf(wv.y, i2b, acc[q][2]); acc[q][2] = fmaf(wv.z, i2c, acc[q][2]);
        acc[q][3] = fmaf(wv.x, i3a, acc[q][3]); acc[q][3] = fmaf(wv.y, i3b, acc[q][3]); acc[q][3] = fmaf(wv.z, i3c, acc[q][3]);
      }
    }
  }
#pragma unroll
  for (int q = 0; q < 4; ++q)
    *(float4*)(y + ((b * CHS + co0 + q) * OH + oh) * OH + 4 * g) =
        make_float4(acc[q][0], acc[q][1], acc[q][2], acc[q][3]);
}

// ---------------- BN stats: per (channel, sub-range) block, few atomics ----------------
__global__ __launch_bounds__(256) void stats_k(const float* __restrict__ y,
                                               float* __restrict__ st,
                                               int HW, int SUB) {
  int c = blockIdx.x / SUB, sub = blockIdx.x % SUB;
  int bpb = MBS / SUB;
  float s = 0.0f, s2 = 0.0f;
  for (int b = sub * bpb; b < (sub + 1) * bpb; ++b) {
    const float* p = y + (b * CHS + c) * HW;
    for (int i = threadIdx.x * 4; i < HW; i += 1024) {
      float4 v = *reinterpret_cast<const float4*>(p + i);
      s  += v.x + v.y + v.z + v.w;
      s2 += v.x * v.x + v.y * v.y + v.z * v.z + v.w * v.w;
    }
  }
#pragma unroll
  for (int off = 1; off < 64; off <<= 1) {
    s  += __shfl_xor(s, off);
    s2 += __shfl_xor(s2, off);
  }
  __shared__ float rs[4], rs2[4];
  int w = threadIdx.x >> 6;
  if ((threadIdx.x & 63) == 0) { rs[w] = s; rs2[w] = s2; }
  __syncthreads();
  if (threadIdx.x == 0) {
    atomicAdd(&st[c * 2 + 0], rs[0] + rs[1] + rs[2] + rs[3]);
    atomicAdd(&st[c * 2 + 1], rs2[0] + rs2[1] + rs2[2] + rs2[3]);
  }
}

// ---------------- BN apply + relu, in place, float4 ----------------
__global__ __launch_bounds__(256) void bn_k(float* __restrict__ y,
                                            const float* __restrict__ st,
                                            const float* __restrict__ g,
                                            const float* __restrict__ beta,
                                            int HW, float inv_cnt) {
  int i4 = (blockIdx.x * 256 + threadIdx.x) * 4;
  int co = (i4 / HW) % CHS;
  float m = st[co * 2 + 0] * inv_cnt;
  float v = st[co * 2 + 1] * inv_cnt - m * m;
  float r = rsqrtf(v + 1e-5f) * g[co];
  float t = beta[co] - m * r;
  float4 vv = *(float4*)(y + i4);
  vv.x = fmaxf(fmaf(vv.x, r, t), 0.0f);
  vv.y = fmaxf(fmaf(vv.y, r, t), 0.0f);
  vv.z = fmaxf(fmaf(vv.z, r, t), 0.0f);
  vv.w = fmaxf(fmaf(vv.w, r, t), 0.0f);
  *(float4*)(y + i4) = vv;
}

// ---------------- fused bn4 + object projections + question projection ----------------
__global__ __launch_bounds__(256) void pre_k(const float* __restrict__ x4raw,
                                             const float* __restrict__ st,
                                             const float* __restrict__ g,
                                             const float* __restrict__ beta,
                                             const float* __restrict__ g1wT,
                                             const float* __restrict__ g1b,
                                             const float* __restrict__ qvec,
                                             float* __restrict__ pre_i,
                                             float* __restrict__ pre_j,
                                             float* __restrict__ pre_q) {
  int bo = blockIdx.x;                                // 4096 obj blocks + 64 q blocks
  int n = threadIdx.x;                                // 256
  __shared__ float sm[QVSS];
  if (bo < 4096) {
    int b = bo >> 6, o = bo & 63;
    if (n < CHS) {
      float m = st[n * 2 + 0] * (1.0f / 4096.0f);
      float v = st[n * 2 + 1] * (1.0f / 4096.0f) - m * m;
      float xv = x4raw[(b * CHS + n) * NOBJS + o];
      sm[n] = fmaxf((xv - m) * rsqrtf(v + 1e-5f) * g[n] + beta[n], 0.0f);
    }
    if (n == 24) sm[24] = (float)(o / 8 - 2) * 0.5f;
    if (n == 25) sm[25] = (float)(o % 8 - 2) * 0.5f;
    __syncthreads();
    float ai = 0.0f, aj = 0.0f;
#pragma unroll
    for (int f = 0; f < 26; ++f) {
      ai += g1wT[f * 256 + n] * sm[f];
      aj += g1wT[(26 + f) * 256 + n] * sm[f];
    }
    pre_i[bo * GS + n] = ai;
    pre_j[bo * GS + n] = aj;
  } else {
    int b = bo - 4096;
    if (n < QVSS) sm[n] = qvec[b * QVSS + n];
    __syncthreads();
    float a = g1b[n];
#pragma unroll
    for (int k = 0; k < QVSS; ++k) a += g1wT[(52 + k) * 256 + n] * sm[k];
    pre_q[b * GS + n] = a;
  }
}

// ---------------- fused relational MLP: 32x32x16 MFMA (FROZEN at (512,4): local optimum) ----------------
// block = (b, j): 64 rows x 256 feats, 8 waves x (64 rows x 32 cols).
// B: global -> VGPR, depth-4 rotating prefetch. A: LDS -> VGPR, depth-2 slot rotation.
// Occupancy axis is CLOSED after 3 failed attempts:
//   r7  (512,2) 8-wave/64-acc: 176us (too few waves);
//   r12 128-row/64-acc at (512,4): spilled (FETCH 155MB);
//   r15 (512,6) 85-reg cap: spilled (FETCH 144MB, arch VGPR squeezed to 40).
// (512,4) measures 143-145us, FETCH 20MB, conflicts 0. Do not touch.
__global__ __launch_bounds__(512, 4) void rel_k(const float* __restrict__ pre_i,
                                                const float* __restrict__ pre_j,
                                                const float* __restrict__ pre_q,
                                                const unsigned short* __restrict__ wbf,
                                                const float* __restrict__ g2b,
                                                const float* __restrict__ g3b,
                                                const float* __restrict__ g4b,
                                                float* __restrict__ xpart) {
  __shared__ short8 hb8[2048];                        // 64 rows x 512 B = 32 KB
  char* hb = (char*)hb8;
  int bid = blockIdx.x;                               // 4096
  int b = bid >> 6, j = bid & 63;
  int tid = threadIdx.x;
  int w = tid >> 6, lane = tid & 63;                  // w = 0..7 (col slice)
  int l31 = lane & 31, lh = lane >> 5;

  const short8* Wt = (const short8*)wbf;              // 52 chunks x [2 kh][256 n] pieces
  const int nA = w * 32 + l31;                        // wave's 32-col slice
  const int pOff = lh * 256 + nA;                     // piece offset within chunk

  // depth-4 B prefetch: chunks 0..3 issued before phase 0 (slot = chunk & 3)
  short8 pa[4];
#pragma unroll
  for (int i = 0; i < 4; ++i) pa[i] = Wt[i * 512 + pOff];

  // phase 0: h0 = relu(pre_j[b,j] + pre_i[b,i] + pre_q[b]); 512 thr: 8 per row
  {
    int r = tid & 63, kc = tid >> 6;
    const float* pj = pre_j + (b * 64 + j) * GS;
    const float* pi = pre_i + (b * 64 + r) * GS;
    const float* pq = pre_q + b * GS;
    int rowbase = r * 512;
    int sw = (r & 31) << 4;
#pragma unroll
    for (int kk = 0; kk < 4; ++kk) {
      int n0 = kc * 32 + kk * 8;
      float4 va  = *(const float4*)(pi + n0);
      float4 va2 = *(const float4*)(pi + n0 + 4);
      float4 vj  = *(const float4*)(pj + n0);
      float4 vj2 = *(const float4*)(pj + n0 + 4);
      float4 vq  = *(const float4*)(pq + n0);
      float4 vq2 = *(const float4*)(pq + n0 + 4);
      short8 pack;
      pack[0] = (short)f2bf(fmaxf(va.x  + vj.x  + vq.x,  0.0f));
      pack[1] = (short)f2bf(fmaxf(va.y  + vj.y  + vq.y,  0.0f));
      pack[2] = (short)f2bf(fmaxf(va.z  + vj.z  + vq.z,  0.0f));
      pack[3] = (short)f2bf(fmaxf(va.w  + vj.w  + vq.w,  0.0f));
      pack[4] = (short)f2bf(fmaxf(va2.x + vj2.x + vq2.x, 0.0f));
      pack[5] = (short)f2bf(fmaxf(va2.y + vj2.y + vq2.y, 0.0f));
      pack[6] = (short)f2bf(fmaxf(va2.z + vj2.z + vq2.z, 0.0f));
      pack[7] = (short)f2bf(fmaxf(va2.w + vj2.w + vq2.w, 0.0f));
      *(short8*)(hb + rowbase + ((n0 * 2) ^ sw)) = pack;
    }
  }
  asm volatile("s_waitcnt lgkmcnt(0)" ::: "memory");
  __builtin_amdgcn_s_barrier();
  __builtin_amdgcn_sched_barrier(0);

  const int rA0 = l31 * 512;
  const int rA1 = (32 + l31) * 512;
  const int swA = l31 << 4;

#pragma unroll 1
  for (int L = 0; L < 3; ++L) {
    const float* bias = (L == 0) ? g2b : ((L == 1) ? g3b : g4b);
    float biasA = bias[nA];
    f32x16 acc0 = {}, acc1 = {};
    // A prologue: fragments for kt = 0,1 (depth-2 slots)
    short8 a0[2], a1[2];
#pragma unroll
    for (int i = 0; i < 2; ++i) {
      int colb = (i * 32 + lh * 16) ^ swA;
      a0[i] = *(const short8*)(hb + rA0 + colb);
      a1[i] = *(const short8*)(hb + rA1 + colb);
    }
#pragma unroll
    for (int kt = 0; kt < 16; ++kt) {
      // issue B for chunk kt+4 first (max vmcnt lead); wbf padded -> no clamp
      short8 nb = Wt[(L * 16 + kt + 4) * 512 + pOff];
      // consume slot kt&1, then refill it for kt+2 (WAR; compiler orders)
      acc0 = __builtin_amdgcn_mfma_f32_32x32x16_bf16(a0[kt & 1], pa[kt & 3], acc0, 0, 0, 0);
      acc1 = __builtin_amdgcn_mfma_f32_32x32x16_bf16(a1[kt & 1], pa[kt & 3], acc1, 0, 0, 0);
      int ktn = (kt < 14) ? kt + 2 : 15;              // compile-time per unrolled iter
      int colb = (ktn * 32 + lh * 16) ^ swA;
      a0[kt & 1] = *(const short8*)(hb + rA0 + colb);
      a1[kt & 1] = *(const short8*)(hb + rA1 + colb);
      pa[kt & 3] = nb;
    }
    // all waves done READING h(L) before anyone rewrites hb
    asm volatile("s_waitcnt lgkmcnt(0)" ::: "memory");
    __builtin_amdgcn_s_barrier();
    __builtin_amdgcn_sched_barrier(0);
    if (L < 2) {
#pragma unroll
      for (int reg = 0; reg < 16; ++reg) {
        int rr = (reg & 3) + 8 * (reg >> 2) + 4 * lh; // 0..31
        int swr = rr << 4;
        unsigned short v0 = f2bf(fmaxf(acc0[reg] + biasA, 0.0f));
        unsigned short v1 = f2bf(fmaxf(acc1[reg] + biasA, 0.0f));
        *(unsigned short*)(hb + rr * 512        + ((nA * 2) ^ swr)) = v0;
        *(unsigned short*)(hb + (32 + rr) * 512 + ((nA * 2) ^ swr)) = v1;
      }
      asm volatile("s_waitcnt lgkmcnt(0)" ::: "memory");
      __builtin_amdgcn_s_barrier();                   // h(L+1) visible
      __builtin_amdgcn_sched_barrier(0);
    } else {
      float sA = 0.0f;
#pragma unroll
      for (int reg = 0; reg < 16; ++reg)
        sA += fmaxf(acc0[reg] + biasA, 0.0f) + fmaxf(acc1[reg] + biasA, 0.0f);
      sA += __shfl_xor(sA, 32);
      float* fs = (float*)hb;
      if (lh == 0) fs[nA] = sA;
      asm volatile("s_waitcnt lgkmcnt(0)" ::: "memory");
      __builtin_amdgcn_s_barrier();
      __builtin_amdgcn_sched_barrier(0);
      if (tid < GS) xpart[bid * GS + tid] = fs[tid];
    }
  }
}

// ---------------- final: reduce xpart over j + f-MLP + log_softmax ----------------
__global__ __launch_bounds__(256) void final_k(const float* __restrict__ xpart,
                                               const float* __restrict__ f1w,
                                               const float* __restrict__ f1b,
                                               const float* __restrict__ f2w,
                                               const float* __restrict__ f2b,
                                               const float* __restrict__ f3w,
                                               const float* __restrict__ f3b,
                                               float* __restrict__ out) {
  int b = blockIdx.x, n = threadIdx.x;
  __shared__ float s0[GS], s1[GS], sl[16];
  float xs = 0.0f;
  for (int j = 0; j < 64; ++j) xs += xpart[(b * 64 + j) * GS + n];
  s0[n] = xs;
  __syncthreads();
  float a = f1b[n];
  {
    const float4* wr = (const float4*)(f1w + n * GS);
    for (int k = 0; k < GS / 4; ++k) {
      float4 wv = wr[k];
      a += wv.x * s0[k * 4] + wv.y * s0[k * 4 + 1] + wv.z * s0[k * 4 + 2] + wv.w * s0[k * 4 + 3];
    }
  }
  s1[n] = fmaxf(a, 0.0f);
  __syncthreads();
  a = f2b[n];
  {
    const float4* wr = (const float4*)(f2w + n * GS);
    for (int k = 0; k < GS / 4; ++k) {
      float4 wv = wr[k];
      a += wv.x * s1[k * 4] + wv.y * s1[k * 4 + 1] + wv.z * s1[k * 4 + 2] + wv.w * s1[k * 4 + 3];
    }
  }
  s0[n] = fmaxf(a, 0.0f);
  __syncthreads();
  if (n < ANSS) {
    a = f3b[n];
    const float4* wr = (const float4*)(f3w + n * GS);
    for (int k = 0; k < GS / 4; ++k) {
      float4 wv = wr[k];
      a += wv.x * s0[k * 4] + wv.y * s0[k * 4 + 1] + wv.z * s0[k * 4 + 2] + wv.w * s0[k * 4 + 3];
    }
    sl[n] = a;
  }
  __syncthreads();
  if (n == 0) {
    float m = -1e30f;
    for (int i = 0; i < ANSS; ++i) m = fmaxf(m, sl[i]);
    float s = 0.0f;
    for (int i = 0; i < ANSS; ++i) s += expf(sl[i] - m);
    sl[12] = m + logf(s);
  }
  __syncthreads();
  if (n < ANSS) out[b * ANSS + n] = sl[n] - sl[12];
}

extern "C" void kernel_launch(void* const* d_in, const int* in_sizes, int n_in,
                              void* d_out, int out_size, void* d_ws, size_t ws_size,
                              hipStream_t stream) {
  const float* image = (const float*)d_in[0];
  const int*   question = (const int*)d_in[1];
  const float* emb = (const float*)d_in[2];
  const float* wih = (const float*)d_in[3];
  const float* whh = (const float*)d_in[4];
  const float* bih = (const float*)d_in[5];
  const float* bhh = (const float*)d_in[6];
  const float* c1w = (const float*)d_in[7];
  const float* c1b = (const float*)d_in[8];
  const float* bn1g = (const float*)d_in[9];
  const float* bn1b = (const float*)d_in[10];
  const float* c2w = (const float*)d_in[11];
  const float* c2b = (const float*)d_in[12];
  const float* bn2g = (const float*)d_in[13];
  const float* bn2b = (const float*)d_in[14];
  const float* c3w = (const float*)d_in[15];
  const float* c3b = (const float*)d_in[16];
  const float* bn3g = (const float*)d_in[17];
  const float* bn3b = (const float*)d_in[18];
  const float* c4w = (const float*)d_in[19];
  const float* c4b = (const float*)d_in[20];
  const float* bn4g = (const float*)d_in[21];
  const float* bn4b = (const float*)d_in[22];
  const float* g1w = (const float*)d_in[23];
  const float* g1b = (const float*)d_in[24];
  const float* g2w = (const float*)d_in[25];
  const float* g2b = (const float*)d_in[26];
  const float* g3w = (const float*)d_in[27];
  const float* g3b = (const float*)d_in[28];
  const float* g4w = (const float*)d_in[29];
  const float* g4b = (const float*)d_in[30];
  const float* f1w = (const float*)d_in[31];
  const float* f1b = (const float*)d_in[32];
  const float* f2w = (const float*)d_in[33];
  const float* f2b = (const float*)d_in[34];
  const float* f3w = (const float*)d_in[35];
  const float* f3b = (const float*)d_in[36];
  float* out = (float*)d_out;

  float* wsf = (float*)d_ws;
  float* arenaA = wsf;                                // 6,291,456 f (y1/y3; later xpart)
  float* arenaB = wsf + 6291456;                      // 1,572,864 f (y2/y4)
  float* qvec   = wsf + 8519680;                      // 8,192 f
  float* pre_i  = wsf + 8527872;                      // 1,048,576 f
  float* pre_j  = wsf + 9576448;                      // 1,048,576 f
  float* pre_q  = wsf + 10625024;                     // 16,384 f
  float* stats  = wsf + 10657792;                     // 256 f (4 layers x 24 x 2)
  unsigned short* wbf = (unsigned short*)(wsf + 10658048); // 52 chunks = 212,992 bf16
  float* g1wT   = wsf + 10764544;                     // 46,080 f
  float* xpart  = arenaA;                             // reuse: convs done before rel_k

  hipMemsetAsync(stats, 0, 256 * sizeof(float), stream);

  prep_k<<<948, 256, 0, stream>>>(g2w, g3w, g4w, wbf, g1w, g1wT);
  lstm_k<<<64, 512, 0, stream>>>(question, emb, wih, bih, bhh, whh, qvec);

  conv_k<3, 128><<<1536, 256, 0, stream>>>(image, c1w, c1b, arenaA);
  stats_k<<<24 * 16, 256, 0, stream>>>(arenaA, stats + 0, 4096, 16);
  bn_k<<<6144, 256, 0, stream>>>(arenaA, stats + 0, bn1g, bn1b, 4096, 1.0f / 262144.0f);

  conv_k<24, 64><<<384, 256, 0, stream>>>(arenaA, c2w, c2b, arenaB);
  stats_k<<<24 * 16, 256, 0, stream>>>(arenaB, stats + 48, 1024, 16);
  bn_k<<<1536, 256, 0, stream>>>(arenaB, stats + 48, bn2g, bn2b, 1024, 1.0f / 65536.0f);

  conv_k<24, 32><<<96, 256, 0, stream>>>(arenaB, c3w, c3b, arenaA);
  stats_k<<<24 * 4, 256, 0, stream>>>(arenaA, stats + 96, 256, 4);
  bn_k<<<384, 256, 0, stream>>>(arenaA, stats + 96, bn3g, bn3b, 256, 1.0f / 16384.0f);

  conv_k<24, 16><<<24, 256, 0, stream>>>(arenaA, c4w, c4b, arenaB);
  stats_k<<<24, 256, 0, stream>>>(arenaB, stats + 144, 64, 1);

  pre_k<<<4096 + 64, 256, 0, stream>>>(arenaB, stats + 144, bn4g, bn4b, g1wT, g1b, qvec,
                                       pre_i, pre_j, pre_q);

  rel_k<<<4096, 512, 0, stream>>>(pre_i, pre_j, pre_q, wbf, g2b, g3b, g4b, xpart);

  final_k<<<64, 256, 0, stream>>>(xpart, f1w, f1b, f2w, f2b, f3w, f3b, out);
}

// Round 17
// 393.593 us; speedup vs baseline: 1.1495x; 1.1495x over previous
//
#include <hip/hip_runtime.h>
#include <math.h>

#define MBS   64
#define QLENS 20
#define EMBS  32
#define QVSS  128
#define ANSS  10
#define CHS   24
#define NOBJS 64
#define GS    256

typedef __attribute__((ext_vector_type(8))) short short8;
typedef __attribute__((ext_vector_type(4))) float f32x4;
typedef __attribute__((ext_vector_type(16))) float f32x16;

__device__ __forceinline__ unsigned short f2bf(float f) {
  unsigned u = __float_as_uint(f);
  u += 0x7fffu + ((u >> 16) & 1u);
  return (unsigned short)(u >> 16);
}
__device__ __forceinline__ float sigm(float x) { return 1.0f / (1.0f + expf(-x)); }

// ---------------- prep: g-weights f32->bf16 [48][2][256][8] + g1w transpose ----------------
// wbf buffer is PADDED to 52 chunks (last 4 uninitialized): rel_k's B-prefetch reads
// pc up to 51 without a clamp; those values never reach an MFMA.
__global__ __launch_bounds__(256) void prep_k(const float* __restrict__ g2w,
                                              const float* __restrict__ g3w,
                                              const float* __restrict__ g4w,
                                              unsigned short* __restrict__ wbf,
                                              const float* __restrict__ g1w,
                                              float* __restrict__ g1wT) {
  int bidx = blockIdx.x;
  if (bidx < 768) {
    int idx = bidx * 256 + threadIdx.x;              // 3*65536
    int l = idx >> 16, r = idx & 65535;
    int kt = r >> 12;
    int rem = r & 4095;
    int kh = rem >> 11;
    int n = (rem >> 3) & 255;
    int e = rem & 7;
    const float* src = (l == 0) ? g2w : ((l == 1) ? g3w : g4w);
    wbf[idx] = f2bf(src[n * 256 + kt * 16 + kh * 8 + e]);
  } else {
    int idx = (bidx - 768) * 256 + threadIdx.x;      // 180*256
    int f = idx >> 8, n = idx & 255;
    g1wT[f * 256 + n] = g1w[n * 180 + f];
  }
}

// ---------------- fused embed+proj + sequential LSTM, one block per batch ----------------
__global__ __launch_bounds__(512) void lstm_k(const int* __restrict__ question,
                                              const float* __restrict__ emb,
                                              const float* __restrict__ wih,
                                              const float* __restrict__ bih,
                                              const float* __restrict__ bhh,
                                              const float* __restrict__ whh,
                                              float* __restrict__ qvec) {
  int b = blockIdx.x;
  int gt = threadIdx.x;                               // 0..511
  __shared__ float h[QVSS];
  __shared__ float gates[4 * QVSS];
  __shared__ int toks[QLENS];
  float w[QVSS];
#pragma unroll
  for (int k = 0; k < QVSS; ++k) w[k] = whh[gt * QVSS + k];
  float wi[EMBS];
#pragma unroll
  for (int k = 0; k < EMBS; ++k) wi[k] = wih[gt * EMBS + k];
  float bb = bih[gt] + bhh[gt];
  if (gt < QLENS) toks[gt] = question[b * QLENS + gt];
  float c = 0.0f;
  if (gt < QVSS) h[gt] = 0.0f;
  __syncthreads();
  float xp[QLENS];
#pragma unroll
  for (int t = 0; t < QLENS; ++t) {
    const float* e = emb + toks[t] * EMBS;
    float a = bb;
#pragma unroll
    for (int k = 0; k < EMBS; ++k) a += wi[k] * e[k];
    xp[t] = a;
  }
  for (int t = 0; t < QLENS; ++t) {
    float acc = xp[t];
#pragma unroll
    for (int k4 = 0; k4 < QVSS / 4; ++k4) {           // float4 LDS reads
      float4 hv = *reinterpret_cast<const float4*>(&h[k4 * 4]);
      acc += w[k4 * 4 + 0] * hv.x + w[k4 * 4 + 1] * hv.y
           + w[k4 * 4 + 2] * hv.z + w[k4 * 4 + 3] * hv.w;
    }
    gates[gt] = acc;
    __syncthreads();
    if (gt < QVSS) {
      float ig = gates[gt];
      float fg = gates[QVSS + gt];
      float gg = gates[2 * QVSS + gt];
      float og = gates[3 * QVSS + gt];
      c = sigm(fg) * c + sigm(ig) * tanhf(gg);
      h[gt] = sigm(og) * tanhf(c);
    }
    __syncthreads();
  }
  if (gt < QVSS) qvec[b * QVSS + gt] = h[gt];
}

// ---------------- direct conv (stride2 pad1 3x3), 8 outputs/thread (2 co x 4 ow) ----------------
// Input loads (2 float4 + 1 edge scalar) shared across the co-pair: 3 loads feed 24 FMA.
// NOTE: co-QUAD (4 co x 4 ow) was tried in r16 and REGRESSED total 393->452 us
// (4x LDS weight reads per input + 16 accs). Co-pair is the measured optimum.
template <int CIN, int H>
__global__ __launch_bounds__(256) void conv_k(const float* __restrict__ x,
                                              const float* __restrict__ w,
                                              const float* __restrict__ bias,
                                              float* __restrict__ y) {
  const int OH = H / 2, GW = OH / 4, CP = CHS / 2;
  __shared__ float4 swp[CHS * CIN * 3];
  __shared__ float sb[CHS];
  for (int i = threadIdx.x; i < CHS * CIN * 3; i += 256) {
    int kh = i % 3, ci = (i / 3) % CIN, co = i / (3 * CIN);
    const float* wp = w + (co * CIN + ci) * 9 + kh * 3;
    swp[i] = make_float4(wp[0], wp[1], wp[2], 0.0f);
  }
  if (threadIdx.x < CHS) sb[threadIdx.x] = bias[threadIdx.x];
  __syncthreads();
  int idx = blockIdx.x * 256 + threadIdx.x;           // 64*12*OH*GW, exact grid
  int g = idx % GW;
  int oh = (idx / GW) % OH;
  int cp = (idx / (GW * OH)) % CP;
  int b  = idx / (CP * OH * GW);
  int co0 = cp * 2, co1 = co0 + 1;
  float a00 = sb[co0], a01 = a00, a02 = a00, a03 = a00;
  float a10 = sb[co1], a11 = a10, a12 = a10, a13 = a10;
  const float* xb = x + b * CIN * H * H;
  const float4* w0 = swp + co0 * CIN * 3;
  const float4* w1 = swp + co1 * CIN * 3;
  bool left = (g > 0);
#pragma unroll
  for (int kh = 0; kh < 3; ++kh) {
    int ih = oh * 2 - 1 + kh;
    if (ih < 0 || ih >= H) continue;
    for (int ci = 0; ci < CIN; ++ci) {
      const float* row = xb + (ci * H + ih) * H + 8 * g;
      float4 v1 = *(const float4*)(row);
      float4 v2 = *(const float4*)(row + 4);
      float am1 = left ? row[-1] : 0.0f;              // zero-pad at iw = -1
      float4 wa = w0[ci * 3 + kh];
      float4 wb = w1[ci * 3 + kh];
      a00 = fmaf(wa.x, am1,  a00); a00 = fmaf(wa.y, v1.x, a00); a00 = fmaf(wa.z, v1.y, a00);
      a01 = fmaf(wa.x, v1.y, a01); a01 = fmaf(wa.y, v1.z, a01); a01 = fmaf(wa.z, v1.w, a01);
      a02 = fmaf(wa.x, v1.w, a02); a02 = fmaf(wa.y, v2.x, a02); a02 = fmaf(wa.z, v2.y, a02);
      a03 = fmaf(wa.x, v2.y, a03); a03 = fmaf(wa.y, v2.z, a03); a03 = fmaf(wa.z, v2.w, a03);
      a10 = fmaf(wb.x, am1,  a10); a10 = fmaf(wb.y, v1.x, a10); a10 = fmaf(wb.z, v1.y, a10);
      a11 = fmaf(wb.x, v1.y, a11); a11 = fmaf(wb.y, v1.z, a11); a11 = fmaf(wb.z, v1.w, a11);
      a12 = fmaf(wb.x, v1.w, a12); a12 = fmaf(wb.y, v2.x, a12); a12 = fmaf(wb.z, v2.y, a12);
      a13 = fmaf(wb.x, v2.y, a13); a13 = fmaf(wb.y, v2.z, a13); a13 = fmaf(wb.z, v2.w, a13);
    }
  }
  *(float4*)(y + ((b * CHS + co0) * OH + oh) * OH + 4 * g) = make_float4(a00, a01, a02, a03);
  *(float4*)(y + ((b * CHS + co1) * OH + oh) * OH + 4 * g) = make_float4(a10, a11, a12, a13);
}

// ---------------- BN stats: per (channel, sub-range) block, few atomics ----------------
__global__ __launch_bounds__(256) void stats_k(const float* __restrict__ y,
                                               float* __restrict__ st,
                                               int HW, int SUB) {
  int c = blockIdx.x / SUB, sub = blockIdx.x % SUB;
  int bpb = MBS / SUB;
  float s = 0.0f, s2 = 0.0f;
  for (int b = sub * bpb; b < (sub + 1) * bpb; ++b) {
    const float* p = y + (b * CHS + c) * HW;
    for (int i = threadIdx.x * 4; i < HW; i += 1024) {
      float4 v = *reinterpret_cast<const float4*>(p + i);
      s  += v.x + v.y + v.z + v.w;
      s2 += v.x * v.x + v.y * v.y + v.z * v.z + v.w * v.w;
    }
  }
#pragma unroll
  for (int off = 1; off < 64; off <<= 1) {
    s  += __shfl_xor(s, off);
    s2 += __shfl_xor(s2, off);
  }
  __shared__ float rs[4], rs2[4];
  int w = threadIdx.x >> 6;
  if ((threadIdx.x & 63) == 0) { rs[w] = s; rs2[w] = s2; }
  __syncthreads();
  if (threadIdx.x == 0) {
    atomicAdd(&st[c * 2 + 0], rs[0] + rs[1] + rs[2] + rs[3]);
    atomicAdd(&st[c * 2 + 1], rs2[0] + rs2[1] + rs2[2] + rs2[3]);
  }
}

// ---------------- BN apply + relu, in place, float4 ----------------
__global__ __launch_bounds__(256) void bn_k(float* __restrict__ y,
                                            const float* __restrict__ st,
                                            const float* __restrict__ g,
                                            const float* __restrict__ beta,
                                            int HW, float inv_cnt) {
  int i4 = (blockIdx.x * 256 + threadIdx.x) * 4;
  int co = (i4 / HW) % CHS;
  float m = st[co * 2 + 0] * inv_cnt;
  float v = st[co * 2 + 1] * inv_cnt - m * m;
  float r = rsqrtf(v + 1e-5f) * g[co];
  float t = beta[co] - m * r;
  float4 vv = *(float4*)(y + i4);
  vv.x = fmaxf(fmaf(vv.x, r, t), 0.0f);
  vv.y = fmaxf(fmaf(vv.y, r, t), 0.0f);
  vv.z = fmaxf(fmaf(vv.z, r, t), 0.0f);
  vv.w = fmaxf(fmaf(vv.w, r, t), 0.0f);
  *(float4*)(y + i4) = vv;
}

// ---------------- fused bn4 + object projections + question projection ----------------
__global__ __launch_bounds__(256) void pre_k(const float* __restrict__ x4raw,
                                             const float* __restrict__ st,
                                             const float* __restrict__ g,
                                             const float* __restrict__ beta,
                                             const float* __restrict__ g1wT,
                                             const float* __restrict__ g1b,
                                             const float* __restrict__ qvec,
                                             float* __restrict__ pre_i,
                                             float* __restrict__ pre_j,
                                             float* __restrict__ pre_q) {
  int bo = blockIdx.x;                                // 4096 obj blocks + 64 q blocks
  int n = threadIdx.x;                                // 256
  __shared__ float sm[QVSS];
  if (bo < 4096) {
    int b = bo >> 6, o = bo & 63;
    if (n < CHS) {
      float m = st[n * 2 + 0] * (1.0f / 4096.0f);
      float v = st[n * 2 + 1] * (1.0f / 4096.0f) - m * m;
      float xv = x4raw[(b * CHS + n) * NOBJS + o];
      sm[n] = fmaxf((xv - m) * rsqrtf(v + 1e-5f) * g[n] + beta[n], 0.0f);
    }
    if (n == 24) sm[24] = (float)(o / 8 - 2) * 0.5f;
    if (n == 25) sm[25] = (float)(o % 8 - 2) * 0.5f;
    __syncthreads();
    float ai = 0.0f, aj = 0.0f;
#pragma unroll
    for (int f = 0; f < 26; ++f) {
      ai += g1wT[f * 256 + n] * sm[f];
      aj += g1wT[(26 + f) * 256 + n] * sm[f];
    }
    pre_i[bo * GS + n] = ai;
    pre_j[bo * GS + n] = aj;
  } else {
    int b = bo - 4096;
    if (n < QVSS) sm[n] = qvec[b * QVSS + n];
    __syncthreads();
    float a = g1b[n];
#pragma unroll
    for (int k = 0; k < QVSS; ++k) a += g1wT[(52 + k) * 256 + n] * sm[k];
    pre_q[b * GS + n] = a;
  }
}

// ---------------- fused relational MLP: 32x32x16 MFMA (FROZEN at (512,4): local optimum) ----------------
// block = (b, j): 64 rows x 256 feats, 8 waves x (64 rows x 32 cols).
// B: global -> VGPR, depth-4 rotating prefetch. A: LDS -> VGPR, depth-2 slot rotation.
// Occupancy axis is CLOSED after 3 failed attempts:
//   r7  (512,2) 8-wave/64-acc: 176us (too few waves);
//   r12 128-row/64-acc at (512,4): spilled (FETCH 155MB);
//   r15 (512,6) 85-reg cap: spilled (FETCH 144MB, arch VGPR squeezed to 40).
// (512,4) measures 143-145us, FETCH 20MB, conflicts 0. Do not touch.
__global__ __launch_bounds__(512, 4) void rel_k(const float* __restrict__ pre_i,
                                                const float* __restrict__ pre_j,
                                                const float* __restrict__ pre_q,
                                                const unsigned short* __restrict__ wbf,
                                                const float* __restrict__ g2b,
                                                const float* __restrict__ g3b,
                                                const float* __restrict__ g4b,
                                                float* __restrict__ xpart) {
  __shared__ short8 hb8[2048];                        // 64 rows x 512 B = 32 KB
  char* hb = (char*)hb8;
  int bid = blockIdx.x;                               // 4096
  int b = bid >> 6, j = bid & 63;
  int tid = threadIdx.x;
  int w = tid >> 6, lane = tid & 63;                  // w = 0..7 (col slice)
  int l31 = lane & 31, lh = lane >> 5;

  const short8* Wt = (const short8*)wbf;              // 52 chunks x [2 kh][256 n] pieces
  const int nA = w * 32 + l31;                        // wave's 32-col slice
  const int pOff = lh * 256 + nA;                     // piece offset within chunk

  // depth-4 B prefetch: chunks 0..3 issued before phase 0 (slot = chunk & 3)
  short8 pa[4];
#pragma unroll
  for (int i = 0; i < 4; ++i) pa[i] = Wt[i * 512 + pOff];

  // phase 0: h0 = relu(pre_j[b,j] + pre_i[b,i] + pre_q[b]); 512 thr: 8 per row
  {
    int r = tid & 63, kc = tid >> 6;
    const float* pj = pre_j + (b * 64 + j) * GS;
    const float* pi = pre_i + (b * 64 + r) * GS;
    const float* pq = pre_q + b * GS;
    int rowbase = r * 512;
    int sw = (r & 31) << 4;
#pragma unroll
    for (int kk = 0; kk < 4; ++kk) {
      int n0 = kc * 32 + kk * 8;
      float4 va  = *(const float4*)(pi + n0);
      float4 va2 = *(const float4*)(pi + n0 + 4);
      float4 vj  = *(const float4*)(pj + n0);
      float4 vj2 = *(const float4*)(pj + n0 + 4);
      float4 vq  = *(const float4*)(pq + n0);
      float4 vq2 = *(const float4*)(pq + n0 + 4);
      short8 pack;
      pack[0] = (short)f2bf(fmaxf(va.x  + vj.x  + vq.x,  0.0f));
      pack[1] = (short)f2bf(fmaxf(va.y  + vj.y  + vq.y,  0.0f));
      pack[2] = (short)f2bf(fmaxf(va.z  + vj.z  + vq.z,  0.0f));
      pack[3] = (short)f2bf(fmaxf(va.w  + vj.w  + vq.w,  0.0f));
      pack[4] = (short)f2bf(fmaxf(va2.x + vj2.x + vq2.x, 0.0f));
      pack[5] = (short)f2bf(fmaxf(va2.y + vj2.y + vq2.y, 0.0f));
      pack[6] = (short)f2bf(fmaxf(va2.z + vj2.z + vq2.z, 0.0f));
      pack[7] = (short)f2bf(fmaxf(va2.w + vj2.w + vq2.w, 0.0f));
      *(short8*)(hb + rowbase + ((n0 * 2) ^ sw)) = pack;
    }
  }
  asm volatile("s_waitcnt lgkmcnt(0)" ::: "memory");
  __builtin_amdgcn_s_barrier();
  __builtin_amdgcn_sched_barrier(0);

  const int rA0 = l31 * 512;
  const int rA1 = (32 + l31) * 512;
  const int swA = l31 << 4;

#pragma unroll 1
  for (int L = 0; L < 3; ++L) {
    const float* bias = (L == 0) ? g2b : ((L == 1) ? g3b : g4b);
    float biasA = bias[nA];
    f32x16 acc0 = {}, acc1 = {};
    // A prologue: fragments for kt = 0,1 (depth-2 slots)
    short8 a0[2], a1[2];
#pragma unroll
    for (int i = 0; i < 2; ++i) {
      int colb = (i * 32 + lh * 16) ^ swA;
      a0[i] = *(const short8*)(hb + rA0 + colb);
      a1[i] = *(const short8*)(hb + rA1 + colb);
    }
#pragma unroll
    for (int kt = 0; kt < 16; ++kt) {
      // issue B for chunk kt+4 first (max vmcnt lead); wbf padded -> no clamp
      short8 nb = Wt[(L * 16 + kt + 4) * 512 + pOff];
      // consume slot kt&1, then refill it for kt+2 (WAR; compiler orders)
      acc0 = __builtin_amdgcn_mfma_f32_32x32x16_bf16(a0[kt & 1], pa[kt & 3], acc0, 0, 0, 0);
      acc1 = __builtin_amdgcn_mfma_f32_32x32x16_bf16(a1[kt & 1], pa[kt & 3], acc1, 0, 0, 0);
      int ktn = (kt < 14) ? kt + 2 : 15;              // compile-time per unrolled iter
      int colb = (ktn * 32 + lh * 16) ^ swA;
      a0[kt & 1] = *(const short8*)(hb + rA0 + colb);
      a1[kt & 1] = *(const short8*)(hb + rA1 + colb);
      pa[kt & 3] = nb;
    }
    // all waves done READING h(L) before anyone rewrites hb
    asm volatile("s_waitcnt lgkmcnt(0)" ::: "memory");
    __builtin_amdgcn_s_barrier();
    __builtin_amdgcn_sched_barrier(0);
    if (L < 2) {
#pragma unroll
      for (int reg = 0; reg < 16; ++reg) {
        int rr = (reg & 3) + 8 * (reg >> 2) + 4 * lh; // 0..31
        int swr = rr << 4;
        unsigned short v0 = f2bf(fmaxf(acc0[reg] + biasA, 0.0f));
        unsigned short v1 = f2bf(fmaxf(acc1[reg] + biasA, 0.0f));
        *(unsigned short*)(hb + rr * 512        + ((nA * 2) ^ swr)) = v0;
        *(unsigned short*)(hb + (32 + rr) * 512 + ((nA * 2) ^ swr)) = v1;
      }
      asm volatile("s_waitcnt lgkmcnt(0)" ::: "memory");
      __builtin_amdgcn_s_barrier();                   // h(L+1) visible
      __builtin_amdgcn_sched_barrier(0);
    } else {
      float sA = 0.0f;
#pragma unroll
      for (int reg = 0; reg < 16; ++reg)
        sA += fmaxf(acc0[reg] + biasA, 0.0f) + fmaxf(acc1[reg] + biasA, 0.0f);
      sA += __shfl_xor(sA, 32);
      float* fs = (float*)hb;
      if (lh == 0) fs[nA] = sA;
      asm volatile("s_waitcnt lgkmcnt(0)" ::: "memory");
      __builtin_amdgcn_s_barrier();
      __builtin_amdgcn_sched_barrier(0);
      if (tid < GS) xpart[bid * GS + tid] = fs[tid];
    }
  }
}

// ---------------- final: reduce xpart over j + f-MLP + log_softmax ----------------
__global__ __launch_bounds__(256) void final_k(const float* __restrict__ xpart,
                                               const float* __restrict__ f1w,
                                               const float* __restrict__ f1b,
                                               const float* __restrict__ f2w,
                                               const float* __restrict__ f2b,
                                               const float* __restrict__ f3w,
                                               const float* __restrict__ f3b,
                                               float* __restrict__ out) {
  int b = blockIdx.x, n = threadIdx.x;
  __shared__ float s0[GS], s1[GS], sl[16];
  float xs = 0.0f;
  for (int j = 0; j < 64; ++j) xs += xpart[(b * 64 + j) * GS + n];
  s0[n] = xs;
  __syncthreads();
  float a = f1b[n];
  {
    const float4* wr = (const float4*)(f1w + n * GS);
    for (int k = 0; k < GS / 4; ++k) {
      float4 wv = wr[k];
      a += wv.x * s0[k * 4] + wv.y * s0[k * 4 + 1] + wv.z * s0[k * 4 + 2] + wv.w * s0[k * 4 + 3];
    }
  }
  s1[n] = fmaxf(a, 0.0f);
  __syncthreads();
  a = f2b[n];
  {
    const float4* wr = (const float4*)(f2w + n * GS);
    for (int k = 0; k < GS / 4; ++k) {
      float4 wv = wr[k];
      a += wv.x * s1[k * 4] + wv.y * s1[k * 4 + 1] + wv.z * s1[k * 4 + 2] + wv.w * s1[k * 4 + 3];
    }
  }
  s0[n] = fmaxf(a, 0.0f);
  __syncthreads();
  if (n < ANSS) {
    a = f3b[n];
    const float4* wr = (const float4*)(f3w + n * GS);
    for (int k = 0; k < GS / 4; ++k) {
      float4 wv = wr[k];
      a += wv.x * s0[k * 4] + wv.y * s0[k * 4 + 1] + wv.z * s0[k * 4 + 2] + wv.w * s0[k * 4 + 3];
    }
    sl[n] = a;
  }
  __syncthreads();
  if (n == 0) {
    float m = -1e30f;
    for (int i = 0; i < ANSS; ++i) m = fmaxf(m, sl[i]);
    float s = 0.0f;
    for (int i = 0; i < ANSS; ++i) s += expf(sl[i] - m);
    sl[12] = m + logf(s);
  }
  __syncthreads();
  if (n < ANSS) out[b * ANSS + n] = sl[n] - sl[12];
}

extern "C" void kernel_launch(void* const* d_in, const int* in_sizes, int n_in,
                              void* d_out, int out_size, void* d_ws, size_t ws_size,
                              hipStream_t stream) {
  const float* image = (const float*)d_in[0];
  const int*   question = (const int*)d_in[1];
  const float* emb = (const float*)d_in[2];
  const float* wih = (const float*)d_in[3];
  const float* whh = (const float*)d_in[4];
  const float* bih = (const float*)d_in[5];
  const float* bhh = (const float*)d_in[6];
  const float* c1w = (const float*)d_in[7];
  const float* c1b = (const float*)d_in[8];
  const float* bn1g = (const float*)d_in[9];
  const float* bn1b = (const float*)d_in[10];
  const float* c2w = (const float*)d_in[11];
  const float* c2b = (const float*)d_in[12];
  const float* bn2g = (const float*)d_in[13];
  const float* bn2b = (const float*)d_in[14];
  const float* c3w = (const float*)d_in[15];
  const float* c3b = (const float*)d_in[16];
  const float* bn3g = (const float*)d_in[17];
  const float* bn3b = (const float*)d_in[18];
  const float* c4w = (const float*)d_in[19];
  const float* c4b = (const float*)d_in[20];
  const float* bn4g = (const float*)d_in[21];
  const float* bn4b = (const float*)d_in[22];
  const float* g1w = (const float*)d_in[23];
  const float* g1b = (const float*)d_in[24];
  const float* g2w = (const float*)d_in[25];
  const float* g2b = (const float*)d_in[26];
  const float* g3w = (const float*)d_in[27];
  const float* g3b = (const float*)d_in[28];
  const float* g4w = (const float*)d_in[29];
  const float* g4b = (const float*)d_in[30];
  const float* f1w = (const float*)d_in[31];
  const float* f1b = (const float*)d_in[32];
  const float* f2w = (const float*)d_in[33];
  const float* f2b = (const float*)d_in[34];
  const float* f3w = (const float*)d_in[35];
  const float* f3b = (const float*)d_in[36];
  float* out = (float*)d_out;

  float* wsf = (float*)d_ws;
  float* arenaA = wsf;                                // 6,291,456 f (y1/y3; later xpart)
  float* arenaB = wsf + 6291456;                      // 1,572,864 f (y2/y4)
  float* qvec   = wsf + 8519680;                      // 8,192 f
  float* pre_i  = wsf + 8527872;                      // 1,048,576 f
  float* pre_j  = wsf + 9576448;                      // 1,048,576 f
  float* pre_q  = wsf + 10625024;                     // 16,384 f
  float* stats  = wsf + 10657792;                     // 256 f (4 layers x 24 x 2)
  unsigned short* wbf = (unsigned short*)(wsf + 10658048); // 52 chunks = 212,992 bf16
  float* g1wT   = wsf + 10764544;                     // 46,080 f
  float* xpart  = arenaA;                             // reuse: convs done before rel_k

  hipMemsetAsync(stats, 0, 256 * sizeof(float), stream);

  prep_k<<<948, 256, 0, stream>>>(g2w, g3w, g4w, wbf, g1w, g1wT);
  lstm_k<<<64, 512, 0, stream>>>(question, emb, wih, bih, bhh, whh, qvec);

  conv_k<3, 128><<<3072, 256, 0, stream>>>(image, c1w, c1b, arenaA);
  stats_k<<<24 * 16, 256, 0, stream>>>(arenaA, stats + 0, 4096, 16);
  bn_k<<<6144, 256, 0, stream>>>(arenaA, stats + 0, bn1g, bn1b, 4096, 1.0f / 262144.0f);

  conv_k<24, 64><<<768, 256, 0, stream>>>(arenaA, c2w, c2b, arenaB);
  stats_k<<<24 * 16, 256, 0, stream>>>(arenaB, stats + 48, 1024, 16);
  bn_k<<<1536, 256, 0, stream>>>(arenaB, stats + 48, bn2g, bn2b, 1024, 1.0f / 65536.0f);

  conv_k<24, 32><<<192, 256, 0, stream>>>(arenaB, c3w, c3b, arenaA);
  stats_k<<<24 * 4, 256, 0, stream>>>(arenaA, stats + 96, 256, 4);
  bn_k<<<384, 256, 0, stream>>>(arenaA, stats + 96, bn3g, bn3b, 256, 1.0f / 16384.0f);

  conv_k<24, 16><<<48, 256, 0, stream>>>(arenaA, c4w, c4b, arenaB);
  stats_k<<<24, 256, 0, stream>>>(arenaB, stats + 144, 64, 1);

  pre_k<<<4096 + 64, 256, 0, stream>>>(arenaB, stats + 144, bn4g, bn4b, g1wT, g1b, qvec,
                                       pre_i, pre_j, pre_q);

  rel_k<<<4096, 512, 0, stream>>>(pre_i, pre_j, pre_q, wbf, g2b, g3b, g4b, xpart);

  final_k<<<64, 256, 0, stream>>>(xpart, f1w, f1b, f2w, f2b, f3w, f3b, out);
}

// Round 19
// 379.637 us; speedup vs baseline: 1.1918x; 1.0368x over previous
//
#include <hip/hip_runtime.h>
#include <math.h>

#define MBS   64
#define QLENS 20
#define EMBS  32
#define QVSS  128
#define ANSS  10
#define CHS   24
#define NOBJS 64
#define GS    256

typedef __attribute__((ext_vector_type(8))) short short8;
typedef __attribute__((ext_vector_type(4))) float f32x4;
typedef __attribute__((ext_vector_type(16))) float f32x16;

__device__ __forceinline__ unsigned short f2bf(float f) {
  unsigned u = __float_as_uint(f);
  u += 0x7fffu + ((u >> 16) & 1u);
  return (unsigned short)(u >> 16);
}
__device__ __forceinline__ float sigm(float x) { return 1.0f / (1.0f + expf(-x)); }

// ---------------- prep: g-weights f32->bf16 [48][2][256][8] + g1w transpose + stats zero ----
// wbf PADDED to 52 chunks (last 4 uninitialized; prefetched but never consumed).
// Block 0 also zeroes the 256-float stats region (replaces a memset dispatch).
__global__ __launch_bounds__(256) void prep_k(const float* __restrict__ g2w,
                                              const float* __restrict__ g3w,
                                              const float* __restrict__ g4w,
                                              unsigned short* __restrict__ wbf,
                                              const float* __restrict__ g1w,
                                              float* __restrict__ g1wT,
                                              float* __restrict__ stats) {
  int bidx = blockIdx.x;
  if (bidx == 0) stats[threadIdx.x] = 0.0f;          // stats_k runs several dispatches later
  if (bidx < 768) {
    int idx = bidx * 256 + threadIdx.x;              // 3*65536
    int l = idx >> 16, r = idx & 65535;
    int kt = r >> 12;
    int rem = r & 4095;
    int kh = rem >> 11;
    int n = (rem >> 3) & 255;
    int e = rem & 7;
    const float* src = (l == 0) ? g2w : ((l == 1) ? g3w : g4w);
    wbf[idx] = f2bf(src[n * 256 + kt * 16 + kh * 8 + e]);
  } else {
    int idx = (bidx - 768) * 256 + threadIdx.x;      // 180*256
    int f = idx >> 8, n = idx & 255;
    g1wT[f * 256 + n] = g1w[n * 180 + f];
  }
}

// ---------------- fused embed+proj + sequential LSTM, one block per batch ----------------
__global__ __launch_bounds__(512) void lstm_k(const int* __restrict__ question,
                                              const float* __restrict__ emb,
                                              const float* __restrict__ wih,
                                              const float* __restrict__ bih,
                                              const float* __restrict__ bhh,
                                              const float* __restrict__ whh,
                                              float* __restrict__ qvec) {
  int b = blockIdx.x;
  int gt = threadIdx.x;                               // 0..511
  __shared__ float h[QVSS];
  __shared__ float gates[4 * QVSS];
  __shared__ int toks[QLENS];
  float w[QVSS];
#pragma unroll
  for (int k = 0; k < QVSS; ++k) w[k] = whh[gt * QVSS + k];
  float wi[EMBS];
#pragma unroll
  for (int k = 0; k < EMBS; ++k) wi[k] = wih[gt * EMBS + k];
  float bb = bih[gt] + bhh[gt];
  if (gt < QLENS) toks[gt] = question[b * QLENS + gt];
  float c = 0.0f;
  if (gt < QVSS) h[gt] = 0.0f;
  __syncthreads();
  float xp[QLENS];
#pragma unroll
  for (int t = 0; t < QLENS; ++t) {
    const float* e = emb + toks[t] * EMBS;
    float a = bb;
#pragma unroll
    for (int k = 0; k < EMBS; ++k) a += wi[k] * e[k];
    xp[t] = a;
  }
  for (int t = 0; t < QLENS; ++t) {
    float acc = xp[t];
#pragma unroll
    for (int k4 = 0; k4 < QVSS / 4; ++k4) {           // float4 LDS reads
      float4 hv = *reinterpret_cast<const float4*>(&h[k4 * 4]);
      acc += w[k4 * 4 + 0] * hv.x + w[k4 * 4 + 1] * hv.y
           + w[k4 * 4 + 2] * hv.z + w[k4 * 4 + 3] * hv.w;
    }
    gates[gt] = acc;
    __syncthreads();
    if (gt < QVSS) {
      float ig = gates[gt];
      float fg = gates[QVSS + gt];
      float gg = gates[2 * QVSS + gt];
      float og = gates[3 * QVSS + gt];
      c = sigm(fg) * c + sigm(ig) * tanhf(gg);
      h[gt] = sigm(og) * tanhf(c);
    }
    __syncthreads();
  }
  if (gt < QVSS) qvec[b * QVSS + gt] = h[gt];
}

// ---------------- direct conv (stride2 pad1 3x3), 8 outputs/thread (2 co x 4 ow) ----------------
// BN=true: input x is RAW previous conv output; apply y=relu(x*ss+stt) inline per loaded
// value (padding stays 0: mask applied AFTER the transform). Structure proven in r5-r8.
// co-pair is the measured optimum (co-quad regressed in r16).
template <int CIN, int H, bool BN>
__global__ __launch_bounds__(256) void conv_k(const float* __restrict__ x,
                                              const float* __restrict__ w,
                                              const float* __restrict__ bias,
                                              float* __restrict__ y,
                                              const float* __restrict__ st,
                                              const float* __restrict__ g,
                                              const float* __restrict__ beta,
                                              float inv_cnt) {
  const int OH = H / 2, GW = OH / 4, CP = CHS / 2;
  __shared__ float4 swp[CHS * CIN * 3];
  __shared__ float sb[CHS];
  __shared__ float ss[CIN], stt[CIN];
  for (int i = threadIdx.x; i < CHS * CIN * 3; i += 256) {
    int kh = i % 3, ci = (i / 3) % CIN, co = i / (3 * CIN);
    const float* wp = w + (co * CIN + ci) * 9 + kh * 3;
    swp[i] = make_float4(wp[0], wp[1], wp[2], 0.0f);
  }
  if (threadIdx.x < CHS) sb[threadIdx.x] = bias[threadIdx.x];
  if (BN && threadIdx.x < CIN) {
    int ci = threadIdx.x;
    float m = st[ci * 2 + 0] * inv_cnt;
    float v = st[ci * 2 + 1] * inv_cnt - m * m;
    float r = rsqrtf(v + 1e-5f);
    ss[ci] = r * g[ci];
    stt[ci] = beta[ci] - m * r * g[ci];
  }
  __syncthreads();
  int idx = blockIdx.x * 256 + threadIdx.x;           // 64*12*OH*GW, exact grid
  int gg = idx % GW;
  int oh = (idx / GW) % OH;
  int cp = (idx / (GW * OH)) % CP;
  int b  = idx / (CP * OH * GW);
  int co0 = cp * 2, co1 = co0 + 1;
  float a00 = sb[co0], a01 = a00, a02 = a00, a03 = a00;
  float a10 = sb[co1], a11 = a10, a12 = a10, a13 = a10;
  const float* xb = x + b * CIN * H * H;
  const float4* w0 = swp + co0 * CIN * 3;
  const float4* w1 = swp + co1 * CIN * 3;
  bool left = (gg > 0);
#pragma unroll
  for (int kh = 0; kh < 3; ++kh) {
    int ih = oh * 2 - 1 + kh;
    if (ih < 0 || ih >= H) continue;
    for (int ci = 0; ci < CIN; ++ci) {
      const float* row = xb + (ci * H + ih) * H + 8 * gg;
      float4 v1 = *(const float4*)(row);
      float4 v2 = *(const float4*)(row + 4);
      float am1 = left ? row[-1] : 0.0f;              // zero-pad at iw = -1
      if (BN) {
        float s = ss[ci], t = stt[ci];
        v1.x = fmaxf(fmaf(v1.x, s, t), 0.0f);
        v1.y = fmaxf(fmaf(v1.y, s, t), 0.0f);
        v1.z = fmaxf(fmaf(v1.z, s, t), 0.0f);
        v1.w = fmaxf(fmaf(v1.w, s, t), 0.0f);
        v2.x = fmaxf(fmaf(v2.x, s, t), 0.0f);
        v2.y = fmaxf(fmaf(v2.y, s, t), 0.0f);
        v2.z = fmaxf(fmaf(v2.z, s, t), 0.0f);
        v2.w = fmaxf(fmaf(v2.w, s, t), 0.0f);
        am1 = left ? fmaxf(fmaf(am1, s, t), 0.0f) : 0.0f;  // pad stays 0
      }
      float4 wa = w0[ci * 3 + kh];
      float4 wb = w1[ci * 3 + kh];
      a00 = fmaf(wa.x, am1,  a00); a00 = fmaf(wa.y, v1.x, a00); a00 = fmaf(wa.z, v1.y, a00);
      a01 = fmaf(wa.x, v1.y, a01); a01 = fmaf(wa.y, v1.z, a01); a01 = fmaf(wa.z, v1.w, a01);
      a02 = fmaf(wa.x, v1.w, a02); a02 = fmaf(wa.y, v2.x, a02); a02 = fmaf(wa.z, v2.y, a02);
      a03 = fmaf(wa.x, v2.y, a03); a03 = fmaf(wa.y, v2.z, a03); a03 = fmaf(wa.z, v2.w, a03);
      a10 = fmaf(wb.x, am1,  a10); a10 = fmaf(wb.y, v1.x, a10); a10 = fmaf(wb.z, v1.y, a10);
      a11 = fmaf(wb.x, v1.y, a11); a11 = fmaf(wb.y, v1.z, a11); a11 = fmaf(wb.z, v1.w, a11);
      a12 = fmaf(wb.x, v1.w, a12); a12 = fmaf(wb.y, v2.x, a12); a12 = fmaf(wb.z, v2.y, a12);
      a13 = fmaf(wb.x, v2.y, a13); a13 = fmaf(wb.y, v2.z, a13); a13 = fmaf(wb.z, v2.w, a13);
    }
  }
  *(float4*)(y + ((b * CHS + co0) * OH + oh) * OH + 4 * gg) = make_float4(a00, a01, a02, a03);
  *(float4*)(y + ((b * CHS + co1) * OH + oh) * OH + 4 * gg) = make_float4(a10, a11, a12, a13);
}

// ---------------- BN stats: per (channel, sub-range) block, few atomics ----------------
__global__ __launch_bounds__(256) void stats_k(const float* __restrict__ y,
                                               float* __restrict__ st,
                                               int HW, int SUB) {
  int c = blockIdx.x / SUB, sub = blockIdx.x % SUB;
  int bpb = MBS / SUB;
  float s = 0.0f, s2 = 0.0f;
  for (int b = sub * bpb; b < (sub + 1) * bpb; ++b) {
    const float* p = y + (b * CHS + c) * HW;
    for (int i = threadIdx.x * 4; i < HW; i += 1024) {
      float4 v = *reinterpret_cast<const float4*>(p + i);
      s  += v.x + v.y + v.z + v.w;
      s2 += v.x * v.x + v.y * v.y + v.z * v.z + v.w * v.w;
    }
  }
#pragma unroll
  for (int off = 1; off < 64; off <<= 1) {
    s  += __shfl_xor(s, off);
    s2 += __shfl_xor(s2, off);
  }
  __shared__ float rs[4], rs2[4];
  int w = threadIdx.x >> 6;
  if ((threadIdx.x & 63) == 0) { rs[w] = s; rs2[w] = s2; }
  __syncthreads();
  if (threadIdx.x == 0) {
    atomicAdd(&st[c * 2 + 0], rs[0] + rs[1] + rs[2] + rs[3]);
    atomicAdd(&st[c * 2 + 1], rs2[0] + rs2[1] + rs2[2] + rs2[3]);
  }
}

// ---------------- fused bn4 + object projections + question projection ----------------
__global__ __launch_bounds__(256) void pre_k(const float* __restrict__ x4raw,
                                             const float* __restrict__ st,
                                             const float* __restrict__ g,
                                             const float* __restrict__ beta,
                                             const float* __restrict__ g1wT,
                                             const float* __restrict__ g1b,
                                             const float* __restrict__ qvec,
                                             float* __restrict__ pre_i,
                                             float* __restrict__ pre_j,
                                             float* __restrict__ pre_q) {
  int bo = blockIdx.x;                                // 4096 obj blocks + 64 q blocks
  int n = threadIdx.x;                                // 256
  __shared__ float sm[QVSS];
  if (bo < 4096) {
    int b = bo >> 6, o = bo & 63;
    if (n < CHS) {
      float m = st[n * 2 + 0] * (1.0f / 4096.0f);
      float v = st[n * 2 + 1] * (1.0f / 4096.0f) - m * m;
      float xv = x4raw[(b * CHS + n) * NOBJS + o];
      sm[n] = fmaxf((xv - m) * rsqrtf(v + 1e-5f) * g[n] + beta[n], 0.0f);
    }
    if (n == 24) sm[24] = (float)(o / 8 - 2) * 0.5f;
    if (n == 25) sm[25] = (float)(o % 8 - 2) * 0.5f;
    __syncthreads();
    float ai = 0.0f, aj = 0.0f;
#pragma unroll
    for (int f = 0; f < 26; ++f) {
      ai += g1wT[f * 256 + n] * sm[f];
      aj += g1wT[(26 + f) * 256 + n] * sm[f];
    }
    pre_i[bo * GS + n] = ai;
    pre_j[bo * GS + n] = aj;
  } else {
    int b = bo - 4096;
    if (n < QVSS) sm[n] = qvec[b * QVSS + n];
    __syncthreads();
    float a = g1b[n];
#pragma unroll
    for (int k = 0; k < QVSS; ++k) a += g1wT[(52 + k) * 256 + n] * sm[k];
    pre_q[b * GS + n] = a;
  }
}

// ---------------- fused relational MLP: 32x32x16 MFMA (FROZEN at (512,4): local optimum) ----------------
// Occupancy axis CLOSED (r7/r12/r15 all regressed or spilled). 143-145us, FETCH 20MB. Do not touch.
__global__ __launch_bounds__(512, 4) void rel_k(const float* __restrict__ pre_i,
                                                const float* __restrict__ pre_j,
                                                const float* __restrict__ pre_q,
                                                const unsigned short* __restrict__ wbf,
                                                const float* __restrict__ g2b,
                                                const float* __restrict__ g3b,
                                                const float* __restrict__ g4b,
                                                float* __restrict__ xpart) {
  __shared__ short8 hb8[2048];                        // 64 rows x 512 B = 32 KB
  char* hb = (char*)hb8;
  int bid = blockIdx.x;                               // 4096
  int b = bid >> 6, j = bid & 63;
  int tid = threadIdx.x;
  int w = tid >> 6, lane = tid & 63;                  // w = 0..7 (col slice)
  int l31 = lane & 31, lh = lane >> 5;

  const short8* Wt = (const short8*)wbf;              // 52 chunks x [2 kh][256 n] pieces
  const int nA = w * 32 + l31;                        // wave's 32-col slice
  const int pOff = lh * 256 + nA;                     // piece offset within chunk

  short8 pa[4];
#pragma unroll
  for (int i = 0; i < 4; ++i) pa[i] = Wt[i * 512 + pOff];

  // phase 0: h0 = relu(pre_j[b,j] + pre_i[b,i] + pre_q[b]); 512 thr: 8 per row
  {
    int r = tid & 63, kc = tid >> 6;
    const float* pj = pre_j + (b * 64 + j) * GS;
    const float* pi = pre_i + (b * 64 + r) * GS;
    const float* pq = pre_q + b * GS;
    int rowbase = r * 512;
    int sw = (r & 31) << 4;
#pragma unroll
    for (int kk = 0; kk < 4; ++kk) {
      int n0 = kc * 32 + kk * 8;
      float4 va  = *(const float4*)(pi + n0);
      float4 va2 = *(const float4*)(pi + n0 + 4);
      float4 vj  = *(const float4*)(pj + n0);
      float4 vj2 = *(const float4*)(pj + n0 + 4);
      float4 vq  = *(const float4*)(pq + n0);
      float4 vq2 = *(const float4*)(pq + n0 + 4);
      short8 pack;
      pack[0] = (short)f2bf(fmaxf(va.x  + vj.x  + vq.x,  0.0f));
      pack[1] = (short)f2bf(fmaxf(va.y  + vj.y  + vq.y,  0.0f));
      pack[2] = (short)f2bf(fmaxf(va.z  + vj.z  + vq.z,  0.0f));
      pack[3] = (short)f2bf(fmaxf(va.w  + vj.w  + vq.w,  0.0f));
      pack[4] = (short)f2bf(fmaxf(va2.x + vj2.x + vq2.x, 0.0f));
      pack[5] = (short)f2bf(fmaxf(va2.y + vj2.y + vq2.y, 0.0f));
      pack[6] = (short)f2bf(fmaxf(va2.z + vj2.z + vq2.z, 0.0f));
      pack[7] = (short)f2bf(fmaxf(va2.w + vj2.w + vq2.w, 0.0f));
      *(short8*)(hb + rowbase + ((n0 * 2) ^ sw)) = pack;
    }
  }
  asm volatile("s_waitcnt lgkmcnt(0)" ::: "memory");
  __builtin_amdgcn_s_barrier();
  __builtin_amdgcn_sched_barrier(0);

  const int rA0 = l31 * 512;
  const int rA1 = (32 + l31) * 512;
  const int swA = l31 << 4;

#pragma unroll 1
  for (int L = 0; L < 3; ++L) {
    const float* bias = (L == 0) ? g2b : ((L == 1) ? g3b : g4b);
    float biasA = bias[nA];
    f32x16 acc0 = {}, acc1 = {};
    short8 a0[2], a1[2];
#pragma unroll
    for (int i = 0; i < 2; ++i) {
      int colb = (i * 32 + lh * 16) ^ swA;
      a0[i] = *(const short8*)(hb + rA0 + colb);
      a1[i] = *(const short8*)(hb + rA1 + colb);
    }
#pragma unroll
    for (int kt = 0; kt < 16; ++kt) {
      short8 nb = Wt[(L * 16 + kt + 4) * 512 + pOff];
      acc0 = __builtin_amdgcn_mfma_f32_32x32x16_bf16(a0[kt & 1], pa[kt & 3], acc0, 0, 0, 0);
      acc1 = __builtin_amdgcn_mfma_f32_32x32x16_bf16(a1[kt & 1], pa[kt & 3], acc1, 0, 0, 0);
      int ktn = (kt < 14) ? kt + 2 : 15;
      int colb = (ktn * 32 + lh * 16) ^ swA;
      a0[kt & 1] = *(const short8*)(hb + rA0 + colb);
      a1[kt & 1] = *(const short8*)(hb + rA1 + colb);
      pa[kt & 3] = nb;
    }
    asm volatile("s_waitcnt lgkmcnt(0)" ::: "memory");
    __builtin_amdgcn_s_barrier();
    __builtin_amdgcn_sched_barrier(0);
    if (L < 2) {
#pragma unroll
      for (int reg = 0; reg < 16; ++reg) {
        int rr = (reg & 3) + 8 * (reg >> 2) + 4 * lh; // 0..31
        int swr = rr << 4;
        unsigned short v0 = f2bf(fmaxf(acc0[reg] + biasA, 0.0f));
        unsigned short v1 = f2bf(fmaxf(acc1[reg] + biasA, 0.0f));
        *(unsigned short*)(hb + rr * 512        + ((nA * 2) ^ swr)) = v0;
        *(unsigned short*)(hb + (32 + rr) * 512 + ((nA * 2) ^ swr)) = v1;
      }
      asm volatile("s_waitcnt lgkmcnt(0)" ::: "memory");
      __builtin_amdgcn_s_barrier();
      __builtin_amdgcn_sched_barrier(0);
    } else {
      float sA = 0.0f;
#pragma unroll
      for (int reg = 0; reg < 16; ++reg)
        sA += fmaxf(acc0[reg] + biasA, 0.0f) + fmaxf(acc1[reg] + biasA, 0.0f);
      sA += __shfl_xor(sA, 32);
      float* fs = (float*)hb;
      if (lh == 0) fs[nA] = sA;
      asm volatile("s_waitcnt lgkmcnt(0)" ::: "memory");
      __builtin_amdgcn_s_barrier();
      __builtin_amdgcn_sched_barrier(0);
      if (tid < GS) xpart[bid * GS + tid] = fs[tid];
    }
  }
}

// ---------------- final: reduce xpart over j + f-MLP + log_softmax ----------------
__global__ __launch_bounds__(256) void final_k(const float* __restrict__ xpart,
                                               const float* __restrict__ f1w,
                                               const float* __restrict__ f1b,
                                               const float* __restrict__ f2w,
                                               const float* __restrict__ f2b,
                                               const float* __restrict__ f3w,
                                               const float* __restrict__ f3b,
                                               float* __restrict__ out) {
  int b = blockIdx.x, n = threadIdx.x;
  __shared__ float s0[GS], s1[GS], sl[16];
  float xs = 0.0f;
  for (int j = 0; j < 64; ++j) xs += xpart[(b * 64 + j) * GS + n];
  s0[n] = xs;
  __syncthreads();
  float a = f1b[n];
  {
    const float4* wr = (const float4*)(f1w + n * GS);
    for (int k = 0; k < GS / 4; ++k) {
      float4 wv = wr[k];
      a += wv.x * s0[k * 4] + wv.y * s0[k * 4 + 1] + wv.z * s0[k * 4 + 2] + wv.w * s0[k * 4 + 3];
    }
  }
  s1[n] = fmaxf(a, 0.0f);
  __syncthreads();
  a = f2b[n];
  {
    const float4* wr = (const float4*)(f2w + n * GS);
    for (int k = 0; k < GS / 4; ++k) {
      float4 wv = wr[k];
      a += wv.x * s1[k * 4] + wv.y * s1[k * 4 + 1] + wv.z * s1[k * 4 + 2] + wv.w * s1[k * 4 + 3];
    }
  }
  s0[n] = fmaxf(a, 0.0f);
  __syncthreads();
  if (n < ANSS) {
    a = f3b[n];
    const float4* wr = (const float4*)(f3w + n * GS);
    for (int k = 0; k < GS / 4; ++k) {
      float4 wv = wr[k];
      a += wv.x * s0[k * 4] + wv.y * s0[k * 4 + 1] + wv.z * s0[k * 4 + 2] + wv.w * s0[k * 4 + 3];
    }
    sl[n] = a;
  }
  __syncthreads();
  if (n == 0) {
    float m = -1e30f;
    for (int i = 0; i < ANSS; ++i) m = fmaxf(m, sl[i]);
    float s = 0.0f;
    for (int i = 0; i < ANSS; ++i) s += expf(sl[i] - m);
    sl[12] = m + logf(s);
  }
  __syncthreads();
  if (n < ANSS) out[b * ANSS + n] = sl[n] - sl[12];
}

extern "C" void kernel_launch(void* const* d_in, const int* in_sizes, int n_in,
                              void* d_out, int out_size, void* d_ws, size_t ws_size,
                              hipStream_t stream) {
  const float* image = (const float*)d_in[0];
  const int*   question = (const int*)d_in[1];
  const float* emb = (const float*)d_in[2];
  const float* wih = (const float*)d_in[3];
  const float* whh = (const float*)d_in[4];
  const float* bih = (const float*)d_in[5];
  const float* bhh = (const float*)d_in[6];
  const float* c1w = (const float*)d_in[7];
  const float* c1b = (const float*)d_in[8];
  const float* bn1g = (const float*)d_in[9];
  const float* bn1b = (const float*)d_in[10];
  const float* c2w = (const float*)d_in[11];
  const float* c2b = (const float*)d_in[12];
  const float* bn2g = (const float*)d_in[13];
  const float* bn2b = (const float*)d_in[14];
  const float* c3w = (const float*)d_in[15];
  const float* c3b = (const float*)d_in[16];
  const float* bn3g = (const float*)d_in[17];
  const float* bn3b = (const float*)d_in[18];
  const float* c4w = (const float*)d_in[19];
  const float* c4b = (const float*)d_in[20];
  const float* bn4g = (const float*)d_in[21];
  const float* bn4b = (const float*)d_in[22];
  const float* g1w = (const float*)d_in[23];
  const float* g1b = (const float*)d_in[24];
  const float* g2w = (const float*)d_in[25];
  const float* g2b = (const float*)d_in[26];
  const float* g3w = (const float*)d_in[27];
  const float* g3b = (const float*)d_in[28];
  const float* g4w = (const float*)d_in[29];
  const float* g4b = (const float*)d_in[30];
  const float* f1w = (const float*)d_in[31];
  const float* f1b = (const float*)d_in[32];
  const float* f2w = (const float*)d_in[33];
  const float* f2b = (const float*)d_in[34];
  const float* f3w = (const float*)d_in[35];
  const float* f3b = (const float*)d_in[36];
  float* out = (float*)d_out;

  float* wsf = (float*)d_ws;
  float* arenaA = wsf;                                // 6,291,456 f (y1/y3; later xpart)
  float* arenaB = wsf + 6291456;                      // 1,572,864 f (y2/y4)
  float* qvec   = wsf + 8519680;                      // 8,192 f
  float* pre_i  = wsf + 8527872;                      // 1,048,576 f
  float* pre_j  = wsf + 9576448;                      // 1,048,576 f
  float* pre_q  = wsf + 10625024;                     // 16,384 f
  float* stats  = wsf + 10657792;                     // 256 f (4 layers x 24 x 2)
  unsigned short* wbf = (unsigned short*)(wsf + 10658048); // 52 chunks = 212,992 bf16
  float* g1wT   = wsf + 10764544;                     // 46,080 f
  float* xpart  = arenaA;                             // reuse: convs done before rel_k

  prep_k<<<948, 256, 0, stream>>>(g2w, g3w, g4w, wbf, g1w, g1wT, stats);
  lstm_k<<<64, 512, 0, stream>>>(question, emb, wih, bih, bhh, whh, qvec);

  conv_k<3, 128, false><<<3072, 256, 0, stream>>>(image, c1w, c1b, arenaA,
                                                  nullptr, nullptr, nullptr, 0.0f);
  stats_k<<<24 * 16, 256, 0, stream>>>(arenaA, stats + 0, 4096, 16);

  conv_k<24, 64, true><<<768, 256, 0, stream>>>(arenaA, c2w, c2b, arenaB,
                                                stats + 0, bn1g, bn1b, 1.0f / 262144.0f);
  stats_k<<<24 * 16, 256, 0, stream>>>(arenaB, stats + 48, 1024, 16);

  conv_k<24, 32, true><<<192, 256, 0, stream>>>(arenaB, c3w, c3b, arenaA,
                                                stats + 48, bn2g, bn2b, 1.0f / 65536.0f);
  stats_k<<<24 * 4, 256, 0, stream>>>(arenaA, stats + 96, 256, 4);

  conv_k<24, 16, true><<<48, 256, 0, stream>>>(arenaA, c4w, c4b, arenaB,
                                               stats + 96, bn3g, bn3b, 1.0f / 16384.0f);
  stats_k<<<24, 256, 0, stream>>>(arenaB, stats + 144, 64, 1);

  pre_k<<<4096 + 64, 256, 0, stream>>>(arenaB, stats + 144, bn4g, bn4b, g1wT, g1b, qvec,
                                       pre_i, pre_j, pre_q);

  rel_k<<<4096, 512, 0, stream>>>(pre_i, pre_j, pre_q, wbf, g2b, g3b, g4b, xpart);

  final_k<<<64, 256, 0, stream>>>(xpart, f1w, f1b, f2w, f2b, f3w, f3b, out);
}

// Round 20
// 338.302 us; speedup vs baseline: 1.3374x; 1.1222x over previous
//
#include <hip/hip_runtime.h>
#include <math.h>

#define MBS   64
#define QLENS 20
#define EMBS  32
#define QVSS  128
#define ANSS  10
#define CHS   24
#define NOBJS 64
#define GS    256
#define NBKT  16

typedef __attribute__((ext_vector_type(8))) short short8;
typedef __attribute__((ext_vector_type(4))) float f32x4;
typedef __attribute__((ext_vector_type(16))) float f32x16;

__device__ __forceinline__ unsigned short f2bf(float f) {
  unsigned u = __float_as_uint(f);
  u += 0x7fffu + ((u >> 16) & 1u);
  return (unsigned short)(u >> 16);
}
__device__ __forceinline__ float sigm(float x) { return 1.0f / (1.0f + expf(-x)); }

// ---------------- prep: g-weights f32->bf16 + g1w transpose + stats zero ----------------
// wbf PADDED to 52 chunks. stats region = 4 layers x 16 buckets x 24 ch x 2 = 3072 f,
// zeroed by blocks 0..11 (replaces a memset dispatch).
__global__ __launch_bounds__(256) void prep_k(const float* __restrict__ g2w,
                                              const float* __restrict__ g3w,
                                              const float* __restrict__ g4w,
                                              unsigned short* __restrict__ wbf,
                                              const float* __restrict__ g1w,
                                              float* __restrict__ g1wT,
                                              float* __restrict__ stats) {
  int bidx = blockIdx.x;
  if (bidx < 12) stats[bidx * 256 + threadIdx.x] = 0.0f;
  if (bidx < 768) {
    int idx = bidx * 256 + threadIdx.x;              // 3*65536
    int l = idx >> 16, r = idx & 65535;
    int kt = r >> 12;
    int rem = r & 4095;
    int kh = rem >> 11;
    int n = (rem >> 3) & 255;
    int e = rem & 7;
    const float* src = (l == 0) ? g2w : ((l == 1) ? g3w : g4w);
    wbf[idx] = f2bf(src[n * 256 + kt * 16 + kh * 8 + e]);
  } else {
    int idx = (bidx - 768) * 256 + threadIdx.x;      // 180*256
    int f = idx >> 8, n = idx & 255;
    g1wT[f * 256 + n] = g1w[n * 180 + f];
  }
}

// ---------------- fused embed+proj + sequential LSTM, one block per batch ----------------
__global__ __launch_bounds__(512) void lstm_k(const int* __restrict__ question,
                                              const float* __restrict__ emb,
                                              const float* __restrict__ wih,
                                              const float* __restrict__ bih,
                                              const float* __restrict__ bhh,
                                              const float* __restrict__ whh,
                                              float* __restrict__ qvec) {
  int b = blockIdx.x;
  int gt = threadIdx.x;                               // 0..511
  __shared__ float h[QVSS];
  __shared__ float gates[4 * QVSS];
  __shared__ int toks[QLENS];
  float w[QVSS];
#pragma unroll
  for (int k = 0; k < QVSS; ++k) w[k] = whh[gt * QVSS + k];
  float wi[EMBS];
#pragma unroll
  for (int k = 0; k < EMBS; ++k) wi[k] = wih[gt * EMBS + k];
  float bb = bih[gt] + bhh[gt];
  if (gt < QLENS) toks[gt] = question[b * QLENS + gt];
  float c = 0.0f;
  if (gt < QVSS) h[gt] = 0.0f;
  __syncthreads();
  float xp[QLENS];
#pragma unroll
  for (int t = 0; t < QLENS; ++t) {
    const float* e = emb + toks[t] * EMBS;
    float a = bb;
#pragma unroll
    for (int k = 0; k < EMBS; ++k) a += wi[k] * e[k];
    xp[t] = a;
  }
  for (int t = 0; t < QLENS; ++t) {
    float acc = xp[t];
#pragma unroll
    for (int k4 = 0; k4 < QVSS / 4; ++k4) {           // float4 LDS reads
      float4 hv = *reinterpret_cast<const float4*>(&h[k4 * 4]);
      acc += w[k4 * 4 + 0] * hv.x + w[k4 * 4 + 1] * hv.y
           + w[k4 * 4 + 2] * hv.z + w[k4 * 4 + 3] * hv.w;
    }
    gates[gt] = acc;
    __syncthreads();
    if (gt < QVSS) {
      float ig = gates[gt];
      float fg = gates[QVSS + gt];
      float gg = gates[2 * QVSS + gt];
      float og = gates[3 * QVSS + gt];
      c = sigm(fg) * c + sigm(ig) * tanhf(gg);
      h[gt] = sigm(og) * tanhf(c);
    }
    __syncthreads();
  }
  if (gt < QVSS) qvec[b * QVSS + gt] = h[gt];
}

// ---------------- conv (stride2 pad1 3x3), 8 out/thread; fused input BN + fused out-stats ----
// BN=true: input transformed y=relu(x*ss+stt) inline (stats summed from 16 buckets).
// Output stats: per-thread raw sums -> TPC-group reduce -> 4 atomics into bucket
// (blockIdx&15): ~21k atomics over 3072 floats total (r1 lesson: contention spread).
template <int CIN, int H, bool BN>
__global__ __launch_bounds__(256) void conv_k(const float* __restrict__ x,
                                              const float* __restrict__ w,
                                              const float* __restrict__ bias,
                                              float* __restrict__ y,
                                              const float* __restrict__ st_in,
                                              const float* __restrict__ g,
                                              const float* __restrict__ beta,
                                              float inv_cnt,
                                              float* __restrict__ st_out) {
  const int OH = H / 2, GW = OH / 4, CP = CHS / 2;
  constexpr int TPC0 = (H / 2) * (H / 8);             // threads covering one co-pair
  constexpr int TPC = (TPC0 >= 256) ? 256 : TPC0;     // 256/256/64/16 for conv1..4
  __shared__ float4 swp[CHS * CIN * 3];
  __shared__ float sb[CHS];
  __shared__ float ss[CIN], stt[CIN];
  __shared__ float red[4][4];
  for (int i = threadIdx.x; i < CHS * CIN * 3; i += 256) {
    int kh = i % 3, ci = (i / 3) % CIN, co = i / (3 * CIN);
    const float* wp = w + (co * CIN + ci) * 9 + kh * 3;
    swp[i] = make_float4(wp[0], wp[1], wp[2], 0.0f);
  }
  if (threadIdx.x < CHS) sb[threadIdx.x] = bias[threadIdx.x];
  if (BN && threadIdx.x < CIN) {
    int ci = threadIdx.x;
    float s = 0.0f, s2 = 0.0f;
    for (int bkt = 0; bkt < NBKT; ++bkt) {
      s  += st_in[(bkt * CHS + ci) * 2 + 0];
      s2 += st_in[(bkt * CHS + ci) * 2 + 1];
    }
    float m = s * inv_cnt;
    float v = s2 * inv_cnt - m * m;
    float r = rsqrtf(v + 1e-5f);
    ss[ci] = r * g[ci];
    stt[ci] = beta[ci] - m * r * g[ci];
  }
  __syncthreads();
  int idx = blockIdx.x * 256 + threadIdx.x;           // 64*12*OH*GW, exact grid
  int gg = idx % GW;
  int oh = (idx / GW) % OH;
  int cp = (idx / (GW * OH)) % CP;
  int b  = idx / (CP * OH * GW);
  int co0 = cp * 2, co1 = co0 + 1;
  float a00 = sb[co0], a01 = a00, a02 = a00, a03 = a00;
  float a10 = sb[co1], a11 = a10, a12 = a10, a13 = a10;
  const float* xb = x + b * CIN * H * H;
  const float4* w0 = swp + co0 * CIN * 3;
  const float4* w1 = swp + co1 * CIN * 3;
  bool left = (gg > 0);
#pragma unroll
  for (int kh = 0; kh < 3; ++kh) {
    int ih = oh * 2 - 1 + kh;
    if (ih < 0 || ih >= H) continue;
    for (int ci = 0; ci < CIN; ++ci) {
      const float* row = xb + (ci * H + ih) * H + 8 * gg;
      float4 v1 = *(const float4*)(row);
      float4 v2 = *(const float4*)(row + 4);
      float am1 = left ? row[-1] : 0.0f;              // zero-pad at iw = -1
      if (BN) {
        float s = ss[ci], t = stt[ci];
        v1.x = fmaxf(fmaf(v1.x, s, t), 0.0f);
        v1.y = fmaxf(fmaf(v1.y, s, t), 0.0f);
        v1.z = fmaxf(fmaf(v1.z, s, t), 0.0f);
        v1.w = fmaxf(fmaf(v1.w, s, t), 0.0f);
        v2.x = fmaxf(fmaf(v2.x, s, t), 0.0f);
        v2.y = fmaxf(fmaf(v2.y, s, t), 0.0f);
        v2.z = fmaxf(fmaf(v2.z, s, t), 0.0f);
        v2.w = fmaxf(fmaf(v2.w, s, t), 0.0f);
        am1 = left ? fmaxf(fmaf(am1, s, t), 0.0f) : 0.0f;  // pad stays 0
      }
      float4 wa = w0[ci * 3 + kh];
      float4 wb = w1[ci * 3 + kh];
      a00 = fmaf(wa.x, am1,  a00); a00 = fmaf(wa.y, v1.x, a00); a00 = fmaf(wa.z, v1.y, a00);
      a01 = fmaf(wa.x, v1.y, a01); a01 = fmaf(wa.y, v1.z, a01); a01 = fmaf(wa.z, v1.w, a01);
      a02 = fmaf(wa.x, v1.w, a02); a02 = fmaf(wa.y, v2.x, a02); a02 = fmaf(wa.z, v2.y, a02);
      a03 = fmaf(wa.x, v2.y, a03); a03 = fmaf(wa.y, v2.z, a03); a03 = fmaf(wa.z, v2.w, a03);
      a10 = fmaf(wb.x, am1,  a10); a10 = fmaf(wb.y, v1.x, a10); a10 = fmaf(wb.z, v1.y, a10);
      a11 = fmaf(wb.x, v1.y, a11); a11 = fmaf(wb.y, v1.z, a11); a11 = fmaf(wb.z, v1.w, a11);
      a12 = fmaf(wb.x, v1.w, a12); a12 = fmaf(wb.y, v2.x, a12); a12 = fmaf(wb.z, v2.y, a12);
      a13 = fmaf(wb.x, v2.y, a13); a13 = fmaf(wb.y, v2.z, a13); a13 = fmaf(wb.z, v2.w, a13);
    }
  }
  *(float4*)(y + ((b * CHS + co0) * OH + oh) * OH + 4 * gg) = make_float4(a00, a01, a02, a03);
  *(float4*)(y + ((b * CHS + co1) * OH + oh) * OH + 4 * gg) = make_float4(a10, a11, a12, a13);

  // fused output stats (raw conv values, as stats_k did)
  float s0 = a00 + a01 + a02 + a03;
  float q0 = a00 * a00 + a01 * a01 + a02 * a02 + a03 * a03;
  float s1 = a10 + a11 + a12 + a13;
  float q1 = a10 * a10 + a11 * a11 + a12 * a12 + a13 * a13;
  constexpr int WR = (TPC < 64) ? TPC : 64;
#pragma unroll
  for (int off = 1; off < WR; off <<= 1) {
    s0 += __shfl_xor(s0, off); q0 += __shfl_xor(q0, off);
    s1 += __shfl_xor(s1, off); q1 += __shfl_xor(q1, off);
  }
  int bkt = blockIdx.x & (NBKT - 1);
  if (TPC == 256) {                                   // whole block one co-pair
    int wv = threadIdx.x >> 6;
    if ((threadIdx.x & 63) == 0) {
      red[wv][0] = s0; red[wv][1] = q0; red[wv][2] = s1; red[wv][3] = q1;
    }
    __syncthreads();
    if (threadIdx.x == 0) {
      atomicAdd(&st_out[(bkt * CHS + co0) * 2 + 0], red[0][0] + red[1][0] + red[2][0] + red[3][0]);
      atomicAdd(&st_out[(bkt * CHS + co0) * 2 + 1], red[0][1] + red[1][1] + red[2][1] + red[3][1]);
      atomicAdd(&st_out[(bkt * CHS + co1) * 2 + 0], red[0][2] + red[1][2] + red[2][2] + red[3][2]);
      atomicAdd(&st_out[(bkt * CHS + co1) * 2 + 1], red[0][3] + red[1][3] + red[2][3] + red[3][3]);
    }
  } else {                                            // TPC-lane groups own a co-pair
    if ((threadIdx.x & (TPC - 1)) == 0) {
      atomicAdd(&st_out[(bkt * CHS + co0) * 2 + 0], s0);
      atomicAdd(&st_out[(bkt * CHS + co0) * 2 + 1], q0);
      atomicAdd(&st_out[(bkt * CHS + co1) * 2 + 0], s1);
      atomicAdd(&st_out[(bkt * CHS + co1) * 2 + 1], q1);
    }
  }
}

// ---------------- fused bn4 + object projections + question projection ----------------
__global__ __launch_bounds__(256) void pre_k(const float* __restrict__ x4raw,
                                             const float* __restrict__ st,
                                             const float* __restrict__ g,
                                             const float* __restrict__ beta,
                                             const float* __restrict__ g1wT,
                                             const float* __restrict__ g1b,
                                             const float* __restrict__ qvec,
                                             float* __restrict__ pre_i,
                                             float* __restrict__ pre_j,
                                             float* __restrict__ pre_q) {
  int bo = blockIdx.x;                                // 4096 obj blocks + 64 q blocks
  int n = threadIdx.x;                                // 256
  __shared__ float sm[QVSS];
  if (bo < 4096) {
    int b = bo >> 6, o = bo & 63;
    if (n < CHS) {
      float s = 0.0f, s2 = 0.0f;
      for (int bkt = 0; bkt < NBKT; ++bkt) {
        s  += st[(bkt * CHS + n) * 2 + 0];
        s2 += st[(bkt * CHS + n) * 2 + 1];
      }
      float m = s * (1.0f / 4096.0f);
      float v = s2 * (1.0f / 4096.0f) - m * m;
      float xv = x4raw[(b * CHS + n) * NOBJS + o];
      sm[n] = fmaxf((xv - m) * rsqrtf(v + 1e-5f) * g[n] + beta[n], 0.0f);
    }
    if (n == 24) sm[24] = (float)(o / 8 - 2) * 0.5f;
    if (n == 25) sm[25] = (float)(o % 8 - 2) * 0.5f;
    __syncthreads();
    float ai = 0.0f, aj = 0.0f;
#pragma unroll
    for (int f = 0; f < 26; ++f) {
      ai += g1wT[f * 256 + n] * sm[f];
      aj += g1wT[(26 + f) * 256 + n] * sm[f];
    }
    pre_i[bo * GS + n] = ai;
    pre_j[bo * GS + n] = aj;
  } else {
    int b = bo - 4096;
    if (n < QVSS) sm[n] = qvec[b * QVSS + n];
    __syncthreads();
    float a = g1b[n];
#pragma unroll
    for (int k = 0; k < QVSS; ++k) a += g1wT[(52 + k) * 256 + n] * sm[k];
    pre_q[b * GS + n] = a;
  }
}

// ---------------- fused relational MLP: 32x32x16 MFMA (FROZEN at (512,4): local optimum) ----------------
// Occupancy axis CLOSED (r7/r12/r15 all regressed or spilled). 143-145us, FETCH 20MB. Do not touch.
__global__ __launch_bounds__(512, 4) void rel_k(const float* __restrict__ pre_i,
                                                const float* __restrict__ pre_j,
                                                const float* __restrict__ pre_q,
                                                const unsigned short* __restrict__ wbf,
                                                const float* __restrict__ g2b,
                                                const float* __restrict__ g3b,
                                                const float* __restrict__ g4b,
                                                float* __restrict__ xpart) {
  __shared__ short8 hb8[2048];                        // 64 rows x 512 B = 32 KB
  char* hb = (char*)hb8;
  int bid = blockIdx.x;                               // 4096
  int b = bid >> 6, j = bid & 63;
  int tid = threadIdx.x;
  int w = tid >> 6, lane = tid & 63;                  // w = 0..7 (col slice)
  int l31 = lane & 31, lh = lane >> 5;

  const short8* Wt = (const short8*)wbf;              // 52 chunks x [2 kh][256 n] pieces
  const int nA = w * 32 + l31;                        // wave's 32-col slice
  const int pOff = lh * 256 + nA;                     // piece offset within chunk

  short8 pa[4];
#pragma unroll
  for (int i = 0; i < 4; ++i) pa[i] = Wt[i * 512 + pOff];

  // phase 0: h0 = relu(pre_j[b,j] + pre_i[b,i] + pre_q[b]); 512 thr: 8 per row
  {
    int r = tid & 63, kc = tid >> 6;
    const float* pj = pre_j + (b * 64 + j) * GS;
    const float* pi = pre_i + (b * 64 + r) * GS;
    const float* pq = pre_q + b * GS;
    int rowbase = r * 512;
    int sw = (r & 31) << 4;
#pragma unroll
    for (int kk = 0; kk < 4; ++kk) {
      int n0 = kc * 32 + kk * 8;
      float4 va  = *(const float4*)(pi + n0);
      float4 va2 = *(const float4*)(pi + n0 + 4);
      float4 vj  = *(const float4*)(pj + n0);
      float4 vj2 = *(const float4*)(pj + n0 + 4);
      float4 vq  = *(const float4*)(pq + n0);
      float4 vq2 = *(const float4*)(pq + n0 + 4);
      short8 pack;
      pack[0] = (short)f2bf(fmaxf(va.x  + vj.x  + vq.x,  0.0f));
      pack[1] = (short)f2bf(fmaxf(va.y  + vj.y  + vq.y,  0.0f));
      pack[2] = (short)f2bf(fmaxf(va.z  + vj.z  + vq.z,  0.0f));
      pack[3] = (short)f2bf(fmaxf(va.w  + vj.w  + vq.w,  0.0f));
      pack[4] = (short)f2bf(fmaxf(va2.x + vj2.x + vq2.x, 0.0f));
      pack[5] = (short)f2bf(fmaxf(va2.y + vj2.y + vq2.y, 0.0f));
      pack[6] = (short)f2bf(fmaxf(va2.z + vj2.z + vq2.z, 0.0f));
      pack[7] = (short)f2bf(fmaxf(va2.w + vj2.w + vq2.w, 0.0f));
      *(short8*)(hb + rowbase + ((n0 * 2) ^ sw)) = pack;
    }
  }
  asm volatile("s_waitcnt lgkmcnt(0)" ::: "memory");
  __builtin_amdgcn_s_barrier();
  __builtin_amdgcn_sched_barrier(0);

  const int rA0 = l31 * 512;
  const int rA1 = (32 + l31) * 512;
  const int swA = l31 << 4;

#pragma unroll 1
  for (int L = 0; L < 3; ++L) {
    const float* bias = (L == 0) ? g2b : ((L == 1) ? g3b : g4b);
    float biasA = bias[nA];
    f32x16 acc0 = {}, acc1 = {};
    short8 a0[2], a1[2];
#pragma unroll
    for (int i = 0; i < 2; ++i) {
      int colb = (i * 32 + lh * 16) ^ swA;
      a0[i] = *(const short8*)(hb + rA0 + colb);
      a1[i] = *(const short8*)(hb + rA1 + colb);
    }
#pragma unroll
    for (int kt = 0; kt < 16; ++kt) {
      short8 nb = Wt[(L * 16 + kt + 4) * 512 + pOff];
      acc0 = __builtin_amdgcn_mfma_f32_32x32x16_bf16(a0[kt & 1], pa[kt & 3], acc0, 0, 0, 0);
      acc1 = __builtin_amdgcn_mfma_f32_32x32x16_bf16(a1[kt & 1], pa[kt & 3], acc1, 0, 0, 0);
      int ktn = (kt < 14) ? kt + 2 : 15;
      int colb = (ktn * 32 + lh * 16) ^ swA;
      a0[kt & 1] = *(const short8*)(hb + rA0 + colb);
      a1[kt & 1] = *(const short8*)(hb + rA1 + colb);
      pa[kt & 3] = nb;
    }
    asm volatile("s_waitcnt lgkmcnt(0)" ::: "memory");
    __builtin_amdgcn_s_barrier();
    __builtin_amdgcn_sched_barrier(0);
    if (L < 2) {
#pragma unroll
      for (int reg = 0; reg < 16; ++reg) {
        int rr = (reg & 3) + 8 * (reg >> 2) + 4 * lh; // 0..31
        int swr = rr << 4;
        unsigned short v0 = f2bf(fmaxf(acc0[reg] + biasA, 0.0f));
        unsigned short v1 = f2bf(fmaxf(acc1[reg] + biasA, 0.0f));
        *(unsigned short*)(hb + rr * 512        + ((nA * 2) ^ swr)) = v0;
        *(unsigned short*)(hb + (32 + rr) * 512 + ((nA * 2) ^ swr)) = v1;
      }
      asm volatile("s_waitcnt lgkmcnt(0)" ::: "memory");
      __builtin_amdgcn_s_barrier();
      __builtin_amdgcn_sched_barrier(0);
    } else {
      float sA = 0.0f;
#pragma unroll
      for (int reg = 0; reg < 16; ++reg)
        sA += fmaxf(acc0[reg] + biasA, 0.0f) + fmaxf(acc1[reg] + biasA, 0.0f);
      sA += __shfl_xor(sA, 32);
      float* fs = (float*)hb;
      if (lh == 0) fs[nA] = sA;
      asm volatile("s_waitcnt lgkmcnt(0)" ::: "memory");
      __builtin_amdgcn_s_barrier();
      __builtin_amdgcn_sched_barrier(0);
      if (tid < GS) xpart[bid * GS + tid] = fs[tid];
    }
  }
}

// ---------------- final: reduce xpart over j + f-MLP + log_softmax ----------------
__global__ __launch_bounds__(256) void final_k(const float* __restrict__ xpart,
                                               const float* __restrict__ f1w,
                                               const float* __restrict__ f1b,
                                               const float* __restrict__ f2w,
                                               const float* __restrict__ f2b,
                                               const float* __restrict__ f3w,
                                               const float* __restrict__ f3b,
                                               float* __restrict__ out) {
  int b = blockIdx.x, n = threadIdx.x;
  __shared__ float s0[GS], s1[GS], sl[16];
  float xs = 0.0f;
  for (int j = 0; j < 64; ++j) xs += xpart[(b * 64 + j) * GS + n];
  s0[n] = xs;
  __syncthreads();
  float a = f1b[n];
  {
    const float4* wr = (const float4*)(f1w + n * GS);
    for (int k = 0; k < GS / 4; ++k) {
      float4 wv = wr[k];
      a += wv.x * s0[k * 4] + wv.y * s0[k * 4 + 1] + wv.z * s0[k * 4 + 2] + wv.w * s0[k * 4 + 3];
    }
  }
  s1[n] = fmaxf(a, 0.0f);
  __syncthreads();
  a = f2b[n];
  {
    const float4* wr = (const float4*)(f2w + n * GS);
    for (int k = 0; k < GS / 4; ++k) {
      float4 wv = wr[k];
      a += wv.x * s1[k * 4] + wv.y * s1[k * 4 + 1] + wv.z * s1[k * 4 + 2] + wv.w * s1[k * 4 + 3];
    }
  }
  s0[n] = fmaxf(a, 0.0f);
  __syncthreads();
  if (n < ANSS) {
    a = f3b[n];
    const float4* wr = (const float4*)(f3w + n * GS);
    for (int k = 0; k < GS / 4; ++k) {
      float4 wv = wr[k];
      a += wv.x * s0[k * 4] + wv.y * s0[k * 4 + 1] + wv.z * s0[k * 4 + 2] + wv.w * s0[k * 4 + 3];
    }
    sl[n] = a;
  }
  __syncthreads();
  if (n == 0) {
    float m = -1e30f;
    for (int i = 0; i < ANSS; ++i) m = fmaxf(m, sl[i]);
    float s = 0.0f;
    for (int i = 0; i < ANSS; ++i) s += expf(sl[i] - m);
    sl[12] = m + logf(s);
  }
  __syncthreads();
  if (n < ANSS) out[b * ANSS + n] = sl[n] - sl[12];
}

extern "C" void kernel_launch(void* const* d_in, const int* in_sizes, int n_in,
                              void* d_out, int out_size, void* d_ws, size_t ws_size,
                              hipStream_t stream) {
  const float* image = (const float*)d_in[0];
  const int*   question = (const int*)d_in[1];
  const float* emb = (const float*)d_in[2];
  const float* wih = (const float*)d_in[3];
  const float* whh = (const float*)d_in[4];
  const float* bih = (const float*)d_in[5];
  const float* bhh = (const float*)d_in[6];
  const float* c1w = (const float*)d_in[7];
  const float* c1b = (const float*)d_in[8];
  const float* bn1g = (const float*)d_in[9];
  const float* bn1b = (const float*)d_in[10];
  const float* c2w = (const float*)d_in[11];
  const float* c2b = (const float*)d_in[12];
  const float* bn2g = (const float*)d_in[13];
  const float* bn2b = (const float*)d_in[14];
  const float* c3w = (const float*)d_in[15];
  const float* c3b = (const float*)d_in[16];
  const float* bn3g = (const float*)d_in[17];
  const float* bn3b = (const float*)d_in[18];
  const float* c4w = (const float*)d_in[19];
  const float* c4b = (const float*)d_in[20];
  const float* bn4g = (const float*)d_in[21];
  const float* bn4b = (const float*)d_in[22];
  const float* g1w = (const float*)d_in[23];
  const float* g1b = (const float*)d_in[24];
  const float* g2w = (const float*)d_in[25];
  const float* g2b = (const float*)d_in[26];
  const float* g3w = (const float*)d_in[27];
  const float* g3b = (const float*)d_in[28];
  const float* g4w = (const float*)d_in[29];
  const float* g4b = (const float*)d_in[30];
  const float* f1w = (const float*)d_in[31];
  const float* f1b = (const float*)d_in[32];
  const float* f2w = (const float*)d_in[33];
  const float* f2b = (const float*)d_in[34];
  const float* f3w = (const float*)d_in[35];
  const float* f3b = (const float*)d_in[36];
  float* out = (float*)d_out;

  float* wsf = (float*)d_ws;
  float* arenaA = wsf;                                // 6,291,456 f (y1/y3; later xpart)
  float* arenaB = wsf + 6291456;                      // 1,572,864 f (y2/y4)
  float* qvec   = wsf + 8519680;                      // 8,192 f
  float* pre_i  = wsf + 8527872;                      // 1,048,576 f
  float* pre_j  = wsf + 9576448;                      // 1,048,576 f
  float* pre_q  = wsf + 10625024;                     // 16,384 f
  float* stats  = wsf + 10657792;                     // 3,072 f (4 layers x 16 bkt x 24 x 2)
  unsigned short* wbf = (unsigned short*)(wsf + 10660864); // 52 chunks = 212,992 bf16
  float* g1wT   = wsf + 10767360;                     // 46,080 f
  float* xpart  = arenaA;                             // reuse: convs done before rel_k

  prep_k<<<948, 256, 0, stream>>>(g2w, g3w, g4w, wbf, g1w, g1wT, stats);
  lstm_k<<<64, 512, 0, stream>>>(question, emb, wih, bih, bhh, whh, qvec);

  conv_k<3, 128, false><<<3072, 256, 0, stream>>>(image, c1w, c1b, arenaA,
                                                  nullptr, nullptr, nullptr, 0.0f,
                                                  stats + 0);
  conv_k<24, 64, true><<<768, 256, 0, stream>>>(arenaA, c2w, c2b, arenaB,
                                                stats + 0, bn1g, bn1b, 1.0f / 262144.0f,
                                                stats + 768);
  conv_k<24, 32, true><<<192, 256, 0, stream>>>(arenaB, c3w, c3b, arenaA,
                                                stats + 768, bn2g, bn2b, 1.0f / 65536.0f,
                                                stats + 1536);
  conv_k<24, 16, true><<<48, 256, 0, stream>>>(arenaA, c4w, c4b, arenaB,
                                               stats + 1536, bn3g, bn3b, 1.0f / 16384.0f,
                                               stats + 2304);

  pre_k<<<4096 + 64, 256, 0, stream>>>(arenaB, stats + 2304, bn4g, bn4b, g1wT, g1b, qvec,
                                       pre_i, pre_j, pre_q);

  rel_k<<<4096, 512, 0, stream>>>(pre_i, pre_j, pre_q, wbf, g2b, g3b, g4b, xpart);

  final_k<<<64, 256, 0, stream>>>(xpart, f1w, f1b, f2w, f2b, f3w, f3b, out);
}

// Round 21
// 335.226 us; speedup vs baseline: 1.3497x; 1.0092x over previous
//
#include <hip/hip_runtime.h>
#include <math.h>

#define MBS   64
#define QLENS 20
#define EMBS  32
#define QVSS  128
#define ANSS  10
#define CHS   24
#define NOBJS 64
#define GS    256
#define NBKT  16

typedef __attribute__((ext_vector_type(8))) short short8;
typedef __attribute__((ext_vector_type(4))) float f32x4;
typedef __attribute__((ext_vector_type(16))) float f32x16;

__device__ __forceinline__ unsigned short f2bf(float f) {
  unsigned u = __float_as_uint(f);
  u += 0x7fffu + ((u >> 16) & 1u);
  return (unsigned short)(u >> 16);
}
__device__ __forceinline__ float sigm(float x) { return 1.0f / (1.0f + expf(-x)); }

// ---------------- head: prep (weights bf16 + g1w transpose + stats zero) | lstm ----------
// Blocks 0..473: prep path, 512 thr each (242,688 elements = 196,608 wbf + 46,080 g1wT).
// Blocks 474..537: lstm, one block per batch element (verbatim r20 body).
// Independent work merged into one dispatch to kill one inter-dispatch gap (r19/r20
// measured ~8-10us per gap). conv1 NOT merged: its 36-reg occupancy profile would be
// destroyed by lstm's ~170-reg budget.
__global__ __launch_bounds__(512) void head_k(const float* __restrict__ g2w,
                                              const float* __restrict__ g3w,
                                              const float* __restrict__ g4w,
                                              unsigned short* __restrict__ wbf,
                                              const float* __restrict__ g1w,
                                              float* __restrict__ g1wT,
                                              float* __restrict__ stats,
                                              const int* __restrict__ question,
                                              const float* __restrict__ emb,
                                              const float* __restrict__ wih,
                                              const float* __restrict__ bih,
                                              const float* __restrict__ bhh,
                                              const float* __restrict__ whh,
                                              float* __restrict__ qvec) {
  __shared__ float h[QVSS];
  __shared__ float gates[4 * QVSS];
  __shared__ int toks[QLENS];
  int bidx = blockIdx.x;
  if (bidx < 474) {
    int gidx = bidx * 512 + threadIdx.x;
    if (gidx < 3072) stats[gidx] = 0.0f;              // 4 layers x 16 bkt x 24 x 2
    if (gidx < 196608) {                              // wbf: [48+4pad][2][256][8]
      int l = gidx >> 16, r = gidx & 65535;
      int kt = r >> 12;
      int rem = r & 4095;
      int kh = rem >> 11;
      int n = (rem >> 3) & 255;
      int e = rem & 7;
      const float* src = (l == 0) ? g2w : ((l == 1) ? g3w : g4w);
      wbf[gidx] = f2bf(src[n * 256 + kt * 16 + kh * 8 + e]);
    } else {                                          // g1wT: [180][256]
      int idx = gidx - 196608;
      int f = idx >> 8, n = idx & 255;
      g1wT[f * 256 + n] = g1w[n * 180 + f];
    }
    return;
  }
  // ---- lstm path ----
  int b = bidx - 474;
  int gt = threadIdx.x;                               // 0..511
  float w[QVSS];
#pragma unroll
  for (int k = 0; k < QVSS; ++k) w[k] = whh[gt * QVSS + k];
  float wi[EMBS];
#pragma unroll
  for (int k = 0; k < EMBS; ++k) wi[k] = wih[gt * EMBS + k];
  float bb = bih[gt] + bhh[gt];
  if (gt < QLENS) toks[gt] = question[b * QLENS + gt];
  float c = 0.0f;
  if (gt < QVSS) h[gt] = 0.0f;
  __syncthreads();
  float xp[QLENS];
#pragma unroll
  for (int t = 0; t < QLENS; ++t) {
    const float* e = emb + toks[t] * EMBS;
    float a = bb;
#pragma unroll
    for (int k = 0; k < EMBS; ++k) a += wi[k] * e[k];
    xp[t] = a;
  }
  for (int t = 0; t < QLENS; ++t) {
    float acc = xp[t];
#pragma unroll
    for (int k4 = 0; k4 < QVSS / 4; ++k4) {           // float4 LDS reads
      float4 hv = *reinterpret_cast<const float4*>(&h[k4 * 4]);
      acc += w[k4 * 4 + 0] * hv.x + w[k4 * 4 + 1] * hv.y
           + w[k4 * 4 + 2] * hv.z + w[k4 * 4 + 3] * hv.w;
    }
    gates[gt] = acc;
    __syncthreads();
    if (gt < QVSS) {
      float ig = gates[gt];
      float fg = gates[QVSS + gt];
      float gg = gates[2 * QVSS + gt];
      float og = gates[3 * QVSS + gt];
      c = sigm(fg) * c + sigm(ig) * tanhf(gg);
      h[gt] = sigm(og) * tanhf(c);
    }
    __syncthreads();
  }
  if (gt < QVSS) qvec[b * QVSS + gt] = h[gt];
}

// ---------------- conv (stride2 pad1 3x3), 8 out/thread; fused input BN + fused out-stats ----
// BN=true: input transformed y=relu(x*ss+stt) inline (stats summed from 16 buckets).
// Output stats: per-thread raw sums -> TPC-group reduce -> 4 atomics into bucket
// (blockIdx&15): ~21k atomics over 3072 floats total (r1 lesson: contention spread).
template <int CIN, int H, bool BN>
__global__ __launch_bounds__(256) void conv_k(const float* __restrict__ x,
                                              const float* __restrict__ w,
                                              const float* __restrict__ bias,
                                              float* __restrict__ y,
                                              const float* __restrict__ st_in,
                                              const float* __restrict__ g,
                                              const float* __restrict__ beta,
                                              float inv_cnt,
                                              float* __restrict__ st_out) {
  const int OH = H / 2, GW = OH / 4, CP = CHS / 2;
  constexpr int TPC0 = (H / 2) * (H / 8);             // threads covering one co-pair
  constexpr int TPC = (TPC0 >= 256) ? 256 : TPC0;     // 256/256/64/16 for conv1..4
  __shared__ float4 swp[CHS * CIN * 3];
  __shared__ float sb[CHS];
  __shared__ float ss[CIN], stt[CIN];
  __shared__ float red[4][4];
  for (int i = threadIdx.x; i < CHS * CIN * 3; i += 256) {
    int kh = i % 3, ci = (i / 3) % CIN, co = i / (3 * CIN);
    const float* wp = w + (co * CIN + ci) * 9 + kh * 3;
    swp[i] = make_float4(wp[0], wp[1], wp[2], 0.0f);
  }
  if (threadIdx.x < CHS) sb[threadIdx.x] = bias[threadIdx.x];
  if (BN && threadIdx.x < CIN) {
    int ci = threadIdx.x;
    float s = 0.0f, s2 = 0.0f;
    for (int bkt = 0; bkt < NBKT; ++bkt) {
      s  += st_in[(bkt * CHS + ci) * 2 + 0];
      s2 += st_in[(bkt * CHS + ci) * 2 + 1];
    }
    float m = s * inv_cnt;
    float v = s2 * inv_cnt - m * m;
    float r = rsqrtf(v + 1e-5f);
    ss[ci] = r * g[ci];
    stt[ci] = beta[ci] - m * r * g[ci];
  }
  __syncthreads();
  int idx = blockIdx.x * 256 + threadIdx.x;           // 64*12*OH*GW, exact grid
  int gg = idx % GW;
  int oh = (idx / GW) % OH;
  int cp = (idx / (GW * OH)) % CP;
  int b  = idx / (CP * OH * GW);
  int co0 = cp * 2, co1 = co0 + 1;
  float a00 = sb[co0], a01 = a00, a02 = a00, a03 = a00;
  float a10 = sb[co1], a11 = a10, a12 = a10, a13 = a10;
  const float* xb = x + b * CIN * H * H;
  const float4* w0 = swp + co0 * CIN * 3;
  const float4* w1 = swp + co1 * CIN * 3;
  bool left = (gg > 0);
#pragma unroll
  for (int kh = 0; kh < 3; ++kh) {
    int ih = oh * 2 - 1 + kh;
    if (ih < 0 || ih >= H) continue;
    for (int ci = 0; ci < CIN; ++ci) {
      const float* row = xb + (ci * H + ih) * H + 8 * gg;
      float4 v1 = *(const float4*)(row);
      float4 v2 = *(const float4*)(row + 4);
      float am1 = left ? row[-1] : 0.0f;              // zero-pad at iw = -1
      if (BN) {
        float s = ss[ci], t = stt[ci];
        v1.x = fmaxf(fmaf(v1.x, s, t), 0.0f);
        v1.y = fmaxf(fmaf(v1.y, s, t), 0.0f);
        v1.z = fmaxf(fmaf(v1.z, s, t), 0.0f);
        v1.w = fmaxf(fmaf(v1.w, s, t), 0.0f);
        v2.x = fmaxf(fmaf(v2.x, s, t), 0.0f);
        v2.y = fmaxf(fmaf(v2.y, s, t), 0.0f);
        v2.z = fmaxf(fmaf(v2.z, s, t), 0.0f);
        v2.w = fmaxf(fmaf(v2.w, s, t), 0.0f);
        am1 = left ? fmaxf(fmaf(am1, s, t), 0.0f) : 0.0f;  // pad stays 0
      }
      float4 wa = w0[ci * 3 + kh];
      float4 wb = w1[ci * 3 + kh];
      a00 = fmaf(wa.x, am1,  a00); a00 = fmaf(wa.y, v1.x, a00); a00 = fmaf(wa.z, v1.y, a00);
      a01 = fmaf(wa.x, v1.y, a01); a01 = fmaf(wa.y, v1.z, a01); a01 = fmaf(wa.z, v1.w, a01);
      a02 = fmaf(wa.x, v1.w, a02); a02 = fmaf(wa.y, v2.x, a02); a02 = fmaf(wa.z, v2.y, a02);
      a03 = fmaf(wa.x, v2.y, a03); a03 = fmaf(wa.y, v2.z, a03); a03 = fmaf(wa.z, v2.w, a03);
      a10 = fmaf(wb.x, am1,  a10); a10 = fmaf(wb.y, v1.x, a10); a10 = fmaf(wb.z, v1.y, a10);
      a11 = fmaf(wb.x, v1.y, a11); a11 = fmaf(wb.y, v1.z, a11); a11 = fmaf(wb.z, v1.w, a11);
      a12 = fmaf(wb.x, v1.w, a12); a12 = fmaf(wb.y, v2.x, a12); a12 = fmaf(wb.z, v2.y, a12);
      a13 = fmaf(wb.x, v2.y, a13); a13 = fmaf(wb.y, v2.z, a13); a13 = fmaf(wb.z, v2.w, a13);
    }
  }
  *(float4*)(y + ((b * CHS + co0) * OH + oh) * OH + 4 * gg) = make_float4(a00, a01, a02, a03);
  *(float4*)(y + ((b * CHS + co1) * OH + oh) * OH + 4 * gg) = make_float4(a10, a11, a12, a13);

  // fused output stats (raw conv values, as stats_k did)
  float s0 = a00 + a01 + a02 + a03;
  float q0 = a00 * a00 + a01 * a01 + a02 * a02 + a03 * a03;
  float s1 = a10 + a11 + a12 + a13;
  float q1 = a10 * a10 + a11 * a11 + a12 * a12 + a13 * a13;
  constexpr int WR = (TPC < 64) ? TPC : 64;
#pragma unroll
  for (int off = 1; off < WR; off <<= 1) {
    s0 += __shfl_xor(s0, off); q0 += __shfl_xor(q0, off);
    s1 += __shfl_xor(s1, off); q1 += __shfl_xor(q1, off);
  }
  int bkt = blockIdx.x & (NBKT - 1);
  if (TPC == 256) {                                   // whole block one co-pair
    int wv = threadIdx.x >> 6;
    if ((threadIdx.x & 63) == 0) {
      red[wv][0] = s0; red[wv][1] = q0; red[wv][2] = s1; red[wv][3] = q1;
    }
    __syncthreads();
    if (threadIdx.x == 0) {
      atomicAdd(&st_out[(bkt * CHS + co0) * 2 + 0], red[0][0] + red[1][0] + red[2][0] + red[3][0]);
      atomicAdd(&st_out[(bkt * CHS + co0) * 2 + 1], red[0][1] + red[1][1] + red[2][1] + red[3][1]);
      atomicAdd(&st_out[(bkt * CHS + co1) * 2 + 0], red[0][2] + red[1][2] + red[2][2] + red[3][2]);
      atomicAdd(&st_out[(bkt * CHS + co1) * 2 + 1], red[0][3] + red[1][3] + red[2][3] + red[3][3]);
    }
  } else {                                            // TPC-lane groups own a co-pair
    if ((threadIdx.x & (TPC - 1)) == 0) {
      atomicAdd(&st_out[(bkt * CHS + co0) * 2 + 0], s0);
      atomicAdd(&st_out[(bkt * CHS + co0) * 2 + 1], q0);
      atomicAdd(&st_out[(bkt * CHS + co1) * 2 + 0], s1);
      atomicAdd(&st_out[(bkt * CHS + co1) * 2 + 1], q1);
    }
  }
}

// ---------------- fused bn4 + object projections + question projection ----------------
__global__ __launch_bounds__(256) void pre_k(const float* __restrict__ x4raw,
                                             const float* __restrict__ st,
                                             const float* __restrict__ g,
                                             const float* __restrict__ beta,
                                             const float* __restrict__ g1wT,
                                             const float* __restrict__ g1b,
                                             const float* __restrict__ qvec,
                                             float* __restrict__ pre_i,
                                             float* __restrict__ pre_j,
                                             float* __restrict__ pre_q) {
  int bo = blockIdx.x;                                // 4096 obj blocks + 64 q blocks
  int n = threadIdx.x;                                // 256
  __shared__ float sm[QVSS];
  if (bo < 4096) {
    int b = bo >> 6, o = bo & 63;
    if (n < CHS) {
      float s = 0.0f, s2 = 0.0f;
      for (int bkt = 0; bkt < NBKT; ++bkt) {
        s  += st[(bkt * CHS + n) * 2 + 0];
        s2 += st[(bkt * CHS + n) * 2 + 1];
      }
      float m = s * (1.0f / 4096.0f);
      float v = s2 * (1.0f / 4096.0f) - m * m;
      float xv = x4raw[(b * CHS + n) * NOBJS + o];
      sm[n] = fmaxf((xv - m) * rsqrtf(v + 1e-5f) * g[n] + beta[n], 0.0f);
    }
    if (n == 24) sm[24] = (float)(o / 8 - 2) * 0.5f;
    if (n == 25) sm[25] = (float)(o % 8 - 2) * 0.5f;
    __syncthreads();
    float ai = 0.0f, aj = 0.0f;
#pragma unroll
    for (int f = 0; f < 26; ++f) {
      ai += g1wT[f * 256 + n] * sm[f];
      aj += g1wT[(26 + f) * 256 + n] * sm[f];
    }
    pre_i[bo * GS + n] = ai;
    pre_j[bo * GS + n] = aj;
  } else {
    int b = bo - 4096;
    if (n < QVSS) sm[n] = qvec[b * QVSS + n];
    __syncthreads();
    float a = g1b[n];
#pragma unroll
    for (int k = 0; k < QVSS; ++k) a += g1wT[(52 + k) * 256 + n] * sm[k];
    pre_q[b * GS + n] = a;
  }
}

// ---------------- fused relational MLP: 32x32x16 MFMA (FROZEN at (512,4): local optimum) ----------------
// Occupancy axis CLOSED (r7/r12/r15 all regressed or spilled). 143-145us, FETCH 20MB. Do not touch.
__global__ __launch_bounds__(512, 4) void rel_k(const float* __restrict__ pre_i,
                                                const float* __restrict__ pre_j,
                                                const float* __restrict__ pre_q,
                                                const unsigned short* __restrict__ wbf,
                                                const float* __restrict__ g2b,
                                                const float* __restrict__ g3b,
                                                const float* __restrict__ g4b,
                                                float* __restrict__ xpart) {
  __shared__ short8 hb8[2048];                        // 64 rows x 512 B = 32 KB
  char* hb = (char*)hb8;
  int bid = blockIdx.x;                               // 4096
  int b = bid >> 6, j = bid & 63;
  int tid = threadIdx.x;
  int w = tid >> 6, lane = tid & 63;                  // w = 0..7 (col slice)
  int l31 = lane & 31, lh = lane >> 5;

  const short8* Wt = (const short8*)wbf;              // 52 chunks x [2 kh][256 n] pieces
  const int nA = w * 32 + l31;                        // wave's 32-col slice
  const int pOff = lh * 256 + nA;                     // piece offset within chunk

  short8 pa[4];
#pragma unroll
  for (int i = 0; i < 4; ++i) pa[i] = Wt[i * 512 + pOff];

  // phase 0: h0 = relu(pre_j[b,j] + pre_i[b,i] + pre_q[b]); 512 thr: 8 per row
  {
    int r = tid & 63, kc = tid >> 6;
    const float* pj = pre_j + (b * 64 + j) * GS;
    const float* pi = pre_i + (b * 64 + r) * GS;
    const float* pq = pre_q + b * GS;
    int rowbase = r * 512;
    int sw = (r & 31) << 4;
#pragma unroll
    for (int kk = 0; kk < 4; ++kk) {
      int n0 = kc * 32 + kk * 8;
      float4 va  = *(const float4*)(pi + n0);
      float4 va2 = *(const float4*)(pi + n0 + 4);
      float4 vj  = *(const float4*)(pj + n0);
      float4 vj2 = *(const float4*)(pj + n0 + 4);
      float4 vq  = *(const float4*)(pq + n0);
      float4 vq2 = *(const float4*)(pq + n0 + 4);
      short8 pack;
      pack[0] = (short)f2bf(fmaxf(va.x  + vj.x  + vq.x,  0.0f));
      pack[1] = (short)f2bf(fmaxf(va.y  + vj.y  + vq.y,  0.0f));
      pack[2] = (short)f2bf(fmaxf(va.z  + vj.z  + vq.z,  0.0f));
      pack[3] = (short)f2bf(fmaxf(va.w  + vj.w  + vq.w,  0.0f));
      pack[4] = (short)f2bf(fmaxf(va2.x + vj2.x + vq2.x, 0.0f));
      pack[5] = (short)f2bf(fmaxf(va2.y + vj2.y + vq2.y, 0.0f));
      pack[6] = (short)f2bf(fmaxf(va2.z + vj2.z + vq2.z, 0.0f));
      pack[7] = (short)f2bf(fmaxf(va2.w + vj2.w + vq2.w, 0.0f));
      *(short8*)(hb + rowbase + ((n0 * 2) ^ sw)) = pack;
    }
  }
  asm volatile("s_waitcnt lgkmcnt(0)" ::: "memory");
  __builtin_amdgcn_s_barrier();
  __builtin_amdgcn_sched_barrier(0);

  const int rA0 = l31 * 512;
  const int rA1 = (32 + l31) * 512;
  const int swA = l31 << 4;

#pragma unroll 1
  for (int L = 0; L < 3; ++L) {
    const float* bias = (L == 0) ? g2b : ((L == 1) ? g3b : g4b);
    float biasA = bias[nA];
    f32x16 acc0 = {}, acc1 = {};
    short8 a0[2], a1[2];
#pragma unroll
    for (int i = 0; i < 2; ++i) {
      int colb = (i * 32 + lh * 16) ^ swA;
      a0[i] = *(const short8*)(hb + rA0 + colb);
      a1[i] = *(const short8*)(hb + rA1 + colb);
    }
#pragma unroll
    for (int kt = 0; kt < 16; ++kt) {
      short8 nb = Wt[(L * 16 + kt + 4) * 512 + pOff];
      acc0 = __builtin_amdgcn_mfma_f32_32x32x16_bf16(a0[kt & 1], pa[kt & 3], acc0, 0, 0, 0);
      acc1 = __builtin_amdgcn_mfma_f32_32x32x16_bf16(a1[kt & 1], pa[kt & 3], acc1, 0, 0, 0);
      int ktn = (kt < 14) ? kt + 2 : 15;
      int colb = (ktn * 32 + lh * 16) ^ swA;
      a0[kt & 1] = *(const short8*)(hb + rA0 + colb);
      a1[kt & 1] = *(const short8*)(hb + rA1 + colb);
      pa[kt & 3] = nb;
    }
    asm volatile("s_waitcnt lgkmcnt(0)" ::: "memory");
    __builtin_amdgcn_s_barrier();
    __builtin_amdgcn_sched_barrier(0);
    if (L < 2) {
#pragma unroll
      for (int reg = 0; reg < 16; ++reg) {
        int rr = (reg & 3) + 8 * (reg >> 2) + 4 * lh; // 0..31
        int swr = rr << 4;
        unsigned short v0 = f2bf(fmaxf(acc0[reg] + biasA, 0.0f));
        unsigned short v1 = f2bf(fmaxf(acc1[reg] + biasA, 0.0f));
        *(unsigned short*)(hb + rr * 512        + ((nA * 2) ^ swr)) = v0;
        *(unsigned short*)(hb + (32 + rr) * 512 + ((nA * 2) ^ swr)) = v1;
      }
      asm volatile("s_waitcnt lgkmcnt(0)" ::: "memory");
      __builtin_amdgcn_s_barrier();
      __builtin_amdgcn_sched_barrier(0);
    } else {
      float sA = 0.0f;
#pragma unroll
      for (int reg = 0; reg < 16; ++reg)
        sA += fmaxf(acc0[reg] + biasA, 0.0f) + fmaxf(acc1[reg] + biasA, 0.0f);
      sA += __shfl_xor(sA, 32);
      float* fs = (float*)hb;
      if (lh == 0) fs[nA] = sA;
      asm volatile("s_waitcnt lgkmcnt(0)" ::: "memory");
      __builtin_amdgcn_s_barrier();
      __builtin_amdgcn_sched_barrier(0);
      if (tid < GS) xpart[bid * GS + tid] = fs[tid];
    }
  }
}

// ---------------- final: reduce xpart over j + f-MLP + log_softmax ----------------
__global__ __launch_bounds__(256) void final_k(const float* __restrict__ xpart,
                                               const float* __restrict__ f1w,
                                               const float* __restrict__ f1b,
                                               const float* __restrict__ f2w,
                                               const float* __restrict__ f2b,
                                               const float* __restrict__ f3w,
                                               const float* __restrict__ f3b,
                                               float* __restrict__ out) {
  int b = blockIdx.x, n = threadIdx.x;
  __shared__ float s0[GS], s1[GS], sl[16];
  float xs = 0.0f;
  for (int j = 0; j < 64; ++j) xs += xpart[(b * 64 + j) * GS + n];
  s0[n] = xs;
  __syncthreads();
  float a = f1b[n];
  {
    const float4* wr = (const float4*)(f1w + n * GS);
    for (int k = 0; k < GS / 4; ++k) {
      float4 wv = wr[k];
      a += wv.x * s0[k * 4] + wv.y * s0[k * 4 + 1] + wv.z * s0[k * 4 + 2] + wv.w * s0[k * 4 + 3];
    }
  }
  s1[n] = fmaxf(a, 0.0f);
  __syncthreads();
  a = f2b[n];
  {
    const float4* wr = (const float4*)(f2w + n * GS);
    for (int k = 0; k < GS / 4; ++k) {
      float4 wv = wr[k];
      a += wv.x * s1[k * 4] + wv.y * s1[k * 4 + 1] + wv.z * s1[k * 4 + 2] + wv.w * s1[k * 4 + 3];
    }
  }
  s0[n] = fmaxf(a, 0.0f);
  __syncthreads();
  if (n < ANSS) {
    a = f3b[n];
    const float4* wr = (const float4*)(f3w + n * GS);
    for (int k = 0; k < GS / 4; ++k) {
      float4 wv = wr[k];
      a += wv.x * s0[k * 4] + wv.y * s0[k * 4 + 1] + wv.z * s0[k * 4 + 2] + wv.w * s0[k * 4 + 3];
    }
    sl[n] = a;
  }
  __syncthreads();
  if (n == 0) {
    float m = -1e30f;
    for (int i = 0; i < ANSS; ++i) m = fmaxf(m, sl[i]);
    float s = 0.0f;
    for (int i = 0; i < ANSS; ++i) s += expf(sl[i] - m);
    sl[12] = m + logf(s);
  }
  __syncthreads();
  if (n < ANSS) out[b * ANSS + n] = sl[n] - sl[12];
}

extern "C" void kernel_launch(void* const* d_in, const int* in_sizes, int n_in,
                              void* d_out, int out_size, void* d_ws, size_t ws_size,
                              hipStream_t stream) {
  const float* image = (const float*)d_in[0];
  const int*   question = (const int*)d_in[1];
  const float* emb = (const float*)d_in[2];
  const float* wih = (const float*)d_in[3];
  const float* whh = (const float*)d_in[4];
  const float* bih = (const float*)d_in[5];
  const float* bhh = (const float*)d_in[6];
  const float* c1w = (const float*)d_in[7];
  const float* c1b = (const float*)d_in[8];
  const float* bn1g = (const float*)d_in[9];
  const float* bn1b = (const float*)d_in[10];
  const float* c2w = (const float*)d_in[11];
  const float* c2b = (const float*)d_in[12];
  const float* bn2g = (const float*)d_in[13];
  const float* bn2b = (const float*)d_in[14];
  const float* c3w = (const float*)d_in[15];
  const float* c3b = (const float*)d_in[16];
  const float* bn3g = (const float*)d_in[17];
  const float* bn3b = (const float*)d_in[18];
  const float* c4w = (const float*)d_in[19];
  const float* c4b = (const float*)d_in[20];
  const float* bn4g = (const float*)d_in[21];
  const float* bn4b = (const float*)d_in[22];
  const float* g1w = (const float*)d_in[23];
  const float* g1b = (const float*)d_in[24];
  const float* g2w = (const float*)d_in[25];
  const float* g2b = (const float*)d_in[26];
  const float* g3w = (const float*)d_in[27];
  const float* g3b = (const float*)d_in[28];
  const float* g4w = (const float*)d_in[29];
  const float* g4b = (const float*)d_in[30];
  const float* f1w = (const float*)d_in[31];
  const float* f1b = (const float*)d_in[32];
  const float* f2w = (const float*)d_in[33];
  const float* f2b = (const float*)d_in[34];
  const float* f3w = (const float*)d_in[35];
  const float* f3b = (const float*)d_in[36];
  float* out = (float*)d_out;

  float* wsf = (float*)d_ws;
  float* arenaA = wsf;                                // 6,291,456 f (y1/y3; later xpart)
  float* arenaB = wsf + 6291456;                      // 1,572,864 f (y2/y4)
  float* qvec   = wsf + 8519680;                      // 8,192 f
  float* pre_i  = wsf + 8527872;                      // 1,048,576 f
  float* pre_j  = wsf + 9576448;                      // 1,048,576 f
  float* pre_q  = wsf + 10625024;                     // 16,384 f
  float* stats  = wsf + 10657792;                     // 3,072 f (4 layers x 16 bkt x 24 x 2)
  unsigned short* wbf = (unsigned short*)(wsf + 10660864); // 52 chunks = 212,992 bf16
  float* g1wT   = wsf + 10767360;                     // 46,080 f
  float* xpart  = arenaA;                             // reuse: convs done before rel_k

  head_k<<<538, 512, 0, stream>>>(g2w, g3w, g4w, wbf, g1w, g1wT, stats,
                                  question, emb, wih, bih, bhh, whh, qvec);

  conv_k<3, 128, false><<<3072, 256, 0, stream>>>(image, c1w, c1b, arenaA,
                                                  nullptr, nullptr, nullptr, 0.0f,
                                                  stats + 0);
  conv_k<24, 64, true><<<768, 256, 0, stream>>>(arenaA, c2w, c2b, arenaB,
                                                stats + 0, bn1g, bn1b, 1.0f / 262144.0f,
                                                stats + 768);
  conv_k<24, 32, true><<<192, 256, 0, stream>>>(arenaB, c3w, c3b, arenaA,
                                                stats + 768, bn2g, bn2b, 1.0f / 65536.0f,
                                                stats + 1536);
  conv_k<24, 16, true><<<48, 256, 0, stream>>>(arenaA, c4w, c4b, arenaB,
                                               stats + 1536, bn3g, bn3b, 1.0f / 16384.0f,
                                               stats + 2304);

  pre_k<<<4096 + 64, 256, 0, stream>>>(arenaB, stats + 2304, bn4g, bn4b, g1wT, g1b, qvec,
                                       pre_i, pre_j, pre_q);

  rel_k<<<4096, 512, 0, stream>>>(pre_i, pre_j, pre_q, wbf, g2b, g3b, g4b, xpart);

  final_k<<<64, 256, 0, stream>>>(xpart, f1w, f1b, f2w, f2b, f3w, f3b, out);
}

// Round 22
// 334.474 us; speedup vs baseline: 1.3527x; 1.0022x over previous
//
#include <hip/hip_runtime.h>
#include <math.h>

#define MBS   64
#define QLENS 20
#define EMBS  32
#define QVSS  128
#define ANSS  10
#define CHS   24
#define NOBJS 64
#define GS    256
#define NBKT  16

typedef __attribute__((ext_vector_type(8))) short short8;
typedef __attribute__((ext_vector_type(4))) float f32x4;
typedef __attribute__((ext_vector_type(16))) float f32x16;

__device__ __forceinline__ unsigned short f2bf(float f) {
  unsigned u = __float_as_uint(f);
  u += 0x7fffu + ((u >> 16) & 1u);
  return (unsigned short)(u >> 16);
}
__device__ __forceinline__ float sigm(float x) { return 1.0f / (1.0f + expf(-x)); }

// ---------------- head: prep (weights bf16 + g1w transpose + stats zero) | lstm ----------
__global__ __launch_bounds__(512) void head_k(const float* __restrict__ g2w,
                                              const float* __restrict__ g3w,
                                              const float* __restrict__ g4w,
                                              unsigned short* __restrict__ wbf,
                                              const float* __restrict__ g1w,
                                              float* __restrict__ g1wT,
                                              float* __restrict__ stats,
                                              const int* __restrict__ question,
                                              const float* __restrict__ emb,
                                              const float* __restrict__ wih,
                                              const float* __restrict__ bih,
                                              const float* __restrict__ bhh,
                                              const float* __restrict__ whh,
                                              float* __restrict__ qvec) {
  __shared__ float h[QVSS];
  __shared__ float gates[4 * QVSS];
  __shared__ int toks[QLENS];
  int bidx = blockIdx.x;
  if (bidx < 474) {
    int gidx = bidx * 512 + threadIdx.x;
    if (gidx < 3072) stats[gidx] = 0.0f;              // 4 layers x 16 bkt x 24 x 2
    if (gidx < 196608) {                              // wbf: [48+4pad][2][256][8]
      int l = gidx >> 16, r = gidx & 65535;
      int kt = r >> 12;
      int rem = r & 4095;
      int kh = rem >> 11;
      int n = (rem >> 3) & 255;
      int e = rem & 7;
      const float* src = (l == 0) ? g2w : ((l == 1) ? g3w : g4w);
      wbf[gidx] = f2bf(src[n * 256 + kt * 16 + kh * 8 + e]);
    } else {                                          // g1wT: [180][256]
      int idx = gidx - 196608;
      int f = idx >> 8, n = idx & 255;
      g1wT[f * 256 + n] = g1w[n * 180 + f];
    }
    return;
  }
  // ---- lstm path ----
  int b = bidx - 474;
  int gt = threadIdx.x;                               // 0..511
  float w[QVSS];
#pragma unroll
  for (int k = 0; k < QVSS; ++k) w[k] = whh[gt * QVSS + k];
  float wi[EMBS];
#pragma unroll
  for (int k = 0; k < EMBS; ++k) wi[k] = wih[gt * EMBS + k];
  float bb = bih[gt] + bhh[gt];
  if (gt < QLENS) toks[gt] = question[b * QLENS + gt];
  float c = 0.0f;
  if (gt < QVSS) h[gt] = 0.0f;
  __syncthreads();
  float xp[QLENS];
#pragma unroll
  for (int t = 0; t < QLENS; ++t) {
    const float* e = emb + toks[t] * EMBS;
    float a = bb;
#pragma unroll
    for (int k = 0; k < EMBS; ++k) a += wi[k] * e[k];
    xp[t] = a;
  }
  for (int t = 0; t < QLENS; ++t) {
    float acc = xp[t];
#pragma unroll
    for (int k4 = 0; k4 < QVSS / 4; ++k4) {           // float4 LDS reads
      float4 hv = *reinterpret_cast<const float4*>(&h[k4 * 4]);
      acc += w[k4 * 4 + 0] * hv.x + w[k4 * 4 + 1] * hv.y
           + w[k4 * 4 + 2] * hv.z + w[k4 * 4 + 3] * hv.w;
    }
    gates[gt] = acc;
    __syncthreads();
    if (gt < QVSS) {
      float ig = gates[gt];
      float fg = gates[QVSS + gt];
      float gg = gates[2 * QVSS + gt];
      float og = gates[3 * QVSS + gt];
      c = sigm(fg) * c + sigm(ig) * tanhf(gg);
      h[gt] = sigm(og) * tanhf(c);
    }
    __syncthreads();
  }
  if (gt < QVSS) qvec[b * QVSS + gt] = h[gt];
}

// ---------------- conv (stride2 pad1 3x3), 8 out/thread; fused input BN + fused out-stats ----
template <int CIN, int H, bool BN>
__global__ __launch_bounds__(256) void conv_k(const float* __restrict__ x,
                                              const float* __restrict__ w,
                                              const float* __restrict__ bias,
                                              float* __restrict__ y,
                                              const float* __restrict__ st_in,
                                              const float* __restrict__ g,
                                              const float* __restrict__ beta,
                                              float inv_cnt,
                                              float* __restrict__ st_out) {
  const int OH = H / 2, GW = OH / 4, CP = CHS / 2;
  constexpr int TPC0 = (H / 2) * (H / 8);             // threads covering one co-pair
  constexpr int TPC = (TPC0 >= 256) ? 256 : TPC0;     // 256/256/64/16 for conv1..4
  __shared__ float4 swp[CHS * CIN * 3];
  __shared__ float sb[CHS];
  __shared__ float ss[CIN], stt[CIN];
  __shared__ float red[4][4];
  for (int i = threadIdx.x; i < CHS * CIN * 3; i += 256) {
    int kh = i % 3, ci = (i / 3) % CIN, co = i / (3 * CIN);
    const float* wp = w + (co * CIN + ci) * 9 + kh * 3;
    swp[i] = make_float4(wp[0], wp[1], wp[2], 0.0f);
  }
  if (threadIdx.x < CHS) sb[threadIdx.x] = bias[threadIdx.x];
  if (BN && threadIdx.x < CIN) {
    int ci = threadIdx.x;
    float s = 0.0f, s2 = 0.0f;
    for (int bkt = 0; bkt < NBKT; ++bkt) {
      s  += st_in[(bkt * CHS + ci) * 2 + 0];
      s2 += st_in[(bkt * CHS + ci) * 2 + 1];
    }
    float m = s * inv_cnt;
    float v = s2 * inv_cnt - m * m;
    float r = rsqrtf(v + 1e-5f);
    ss[ci] = r * g[ci];
    stt[ci] = beta[ci] - m * r * g[ci];
  }
  __syncthreads();
  int idx = blockIdx.x * 256 + threadIdx.x;           // 64*12*OH*GW, exact grid
  int gg = idx % GW;
  int oh = (idx / GW) % OH;
  int cp = (idx / (GW * OH)) % CP;
  int b  = idx / (CP * OH * GW);
  int co0 = cp * 2, co1 = co0 + 1;
  float a00 = sb[co0], a01 = a00, a02 = a00, a03 = a00;
  float a10 = sb[co1], a11 = a10, a12 = a10, a13 = a10;
  const float* xb = x + b * CIN * H * H;
  const float4* w0 = swp + co0 * CIN * 3;
  const float4* w1 = swp + co1 * CIN * 3;
  bool left = (gg > 0);
#pragma unroll
  for (int kh = 0; kh < 3; ++kh) {
    int ih = oh * 2 - 1 + kh;
    if (ih < 0 || ih >= H) continue;
    for (int ci = 0; ci < CIN; ++ci) {
      const float* row = xb + (ci * H + ih) * H + 8 * gg;
      float4 v1 = *(const float4*)(row);
      float4 v2 = *(const float4*)(row + 4);
      float am1 = left ? row[-1] : 0.0f;              // zero-pad at iw = -1
      if (BN) {
        float s = ss[ci], t = stt[ci];
        v1.x = fmaxf(fmaf(v1.x, s, t), 0.0f);
        v1.y = fmaxf(fmaf(v1.y, s, t), 0.0f);
        v1.z = fmaxf(fmaf(v1.z, s, t), 0.0f);
        v1.w = fmaxf(fmaf(v1.w, s, t), 0.0f);
        v2.x = fmaxf(fmaf(v2.x, s, t), 0.0f);
        v2.y = fmaxf(fmaf(v2.y, s, t), 0.0f);
        v2.z = fmaxf(fmaf(v2.z, s, t), 0.0f);
        v2.w = fmaxf(fmaf(v2.w, s, t), 0.0f);
        am1 = left ? fmaxf(fmaf(am1, s, t), 0.0f) : 0.0f;  // pad stays 0
      }
      float4 wa = w0[ci * 3 + kh];
      float4 wb = w1[ci * 3 + kh];
      a00 = fmaf(wa.x, am1,  a00); a00 = fmaf(wa.y, v1.x, a00); a00 = fmaf(wa.z, v1.y, a00);
      a01 = fmaf(wa.x, v1.y, a01); a01 = fmaf(wa.y, v1.z, a01); a01 = fmaf(wa.z, v1.w, a01);
      a02 = fmaf(wa.x, v1.w, a02); a02 = fmaf(wa.y, v2.x, a02); a02 = fmaf(wa.z, v2.y, a02);
      a03 = fmaf(wa.x, v2.y, a03); a03 = fmaf(wa.y, v2.z, a03); a03 = fmaf(wa.z, v2.w, a03);
      a10 = fmaf(wb.x, am1,  a10); a10 = fmaf(wb.y, v1.x, a10); a10 = fmaf(wb.z, v1.y, a10);
      a11 = fmaf(wb.x, v1.y, a11); a11 = fmaf(wb.y, v1.z, a11); a11 = fmaf(wb.z, v1.w, a11);
      a12 = fmaf(wb.x, v1.w, a12); a12 = fmaf(wb.y, v2.x, a12); a12 = fmaf(wb.z, v2.y, a12);
      a13 = fmaf(wb.x, v2.y, a13); a13 = fmaf(wb.y, v2.z, a13); a13 = fmaf(wb.z, v2.w, a13);
    }
  }
  *(float4*)(y + ((b * CHS + co0) * OH + oh) * OH + 4 * gg) = make_float4(a00, a01, a02, a03);
  *(float4*)(y + ((b * CHS + co1) * OH + oh) * OH + 4 * gg) = make_float4(a10, a11, a12, a13);

  // fused output stats (raw conv values)
  float s0 = a00 + a01 + a02 + a03;
  float q0 = a00 * a00 + a01 * a01 + a02 * a02 + a03 * a03;
  float s1 = a10 + a11 + a12 + a13;
  float q1 = a10 * a10 + a11 * a11 + a12 * a12 + a13 * a13;
  constexpr int WR = (TPC < 64) ? TPC : 64;
#pragma unroll
  for (int off = 1; off < WR; off <<= 1) {
    s0 += __shfl_xor(s0, off); q0 += __shfl_xor(q0, off);
    s1 += __shfl_xor(s1, off); q1 += __shfl_xor(q1, off);
  }
  int bkt = blockIdx.x & (NBKT - 1);
  if (TPC == 256) {                                   // whole block one co-pair
    int wv = threadIdx.x >> 6;
    if ((threadIdx.x & 63) == 0) {
      red[wv][0] = s0; red[wv][1] = q0; red[wv][2] = s1; red[wv][3] = q1;
    }
    __syncthreads();
    if (threadIdx.x == 0) {
      atomicAdd(&st_out[(bkt * CHS + co0) * 2 + 0], red[0][0] + red[1][0] + red[2][0] + red[3][0]);
      atomicAdd(&st_out[(bkt * CHS + co0) * 2 + 1], red[0][1] + red[1][1] + red[2][1] + red[3][1]);
      atomicAdd(&st_out[(bkt * CHS + co1) * 2 + 0], red[0][2] + red[1][2] + red[2][2] + red[3][2]);
      atomicAdd(&st_out[(bkt * CHS + co1) * 2 + 1], red[0][3] + red[1][3] + red[2][3] + red[3][3]);
    }
  } else {                                            // TPC-lane groups own a co-pair
    if ((threadIdx.x & (TPC - 1)) == 0) {
      atomicAdd(&st_out[(bkt * CHS + co0) * 2 + 0], s0);
      atomicAdd(&st_out[(bkt * CHS + co0) * 2 + 1], q0);
      atomicAdd(&st_out[(bkt * CHS + co1) * 2 + 0], s1);
      atomicAdd(&st_out[(bkt * CHS + co1) * 2 + 1], q1);
    }
  }
}

// ---------------- fused bn4 + object projections + question projection ----------------
__global__ __launch_bounds__(256) void pre_k(const float* __restrict__ x4raw,
                                             const float* __restrict__ st,
                                             const float* __restrict__ g,
                                             const float* __restrict__ beta,
                                             const float* __restrict__ g1wT,
                                             const float* __restrict__ g1b,
                                             const float* __restrict__ qvec,
                                             float* __restrict__ pre_i,
                                             float* __restrict__ pre_j,
                                             float* __restrict__ pre_q) {
  int bo = blockIdx.x;                                // 4096 obj blocks + 64 q blocks
  int n = threadIdx.x;                                // 256
  __shared__ float sm[QVSS];
  if (bo < 4096) {
    int b = bo >> 6, o = bo & 63;
    if (n < CHS) {
      float s = 0.0f, s2 = 0.0f;
      for (int bkt = 0; bkt < NBKT; ++bkt) {
        s  += st[(bkt * CHS + n) * 2 + 0];
        s2 += st[(bkt * CHS + n) * 2 + 1];
      }
      float m = s * (1.0f / 4096.0f);
      float v = s2 * (1.0f / 4096.0f) - m * m;
      float xv = x4raw[(b * CHS + n) * NOBJS + o];
      sm[n] = fmaxf((xv - m) * rsqrtf(v + 1e-5f) * g[n] + beta[n], 0.0f);
    }
    if (n == 24) sm[24] = (float)(o / 8 - 2) * 0.5f;
    if (n == 25) sm[25] = (float)(o % 8 - 2) * 0.5f;
    __syncthreads();
    float ai = 0.0f, aj = 0.0f;
#pragma unroll
    for (int f = 0; f < 26; ++f) {
      ai += g1wT[f * 256 + n] * sm[f];
      aj += g1wT[(26 + f) * 256 + n] * sm[f];
    }
    pre_i[bo * GS + n] = ai;
    pre_j[bo * GS + n] = aj;
  } else {
    int b = bo - 4096;
    if (n < QVSS) sm[n] = qvec[b * QVSS + n];
    __syncthreads();
    float a = g1b[n];
#pragma unroll
    for (int k = 0; k < QVSS; ++k) a += g1wT[(52 + k) * 256 + n] * sm[k];
    pre_q[b * GS + n] = a;
  }
}

// ---------------- fused relational MLP: 32x32x16 MFMA, double-buffered h ----------------
// Geometry FROZEN at (512,4) col-split (r7/r12/r15 closed). NEW vs r21: h is
// double-buffered (2 x 32KB; layer L reads buf[L&1], epilogue writes buf[~L&1]) so the
// "reads-done" barrier per layer is provably unnecessary -> barriers 7 -> 4.
// LDS 64KB/block keeps 2 blocks/CU (128 <= 160KB).
__global__ __launch_bounds__(512, 4) void rel_k(const float* __restrict__ pre_i,
                                                const float* __restrict__ pre_j,
                                                const float* __restrict__ pre_q,
                                                const unsigned short* __restrict__ wbf,
                                                const float* __restrict__ g2b,
                                                const float* __restrict__ g3b,
                                                const float* __restrict__ g4b,
                                                float* __restrict__ xpart) {
  __shared__ short8 hb8[4096];                        // 2 buffers x 64 rows x 512 B
  char* hb = (char*)hb8;
  int bid = blockIdx.x;                               // 4096
  int b = bid >> 6, j = bid & 63;
  int tid = threadIdx.x;
  int w = tid >> 6, lane = tid & 63;                  // w = 0..7 (col slice)
  int l31 = lane & 31, lh = lane >> 5;

  const short8* Wt = (const short8*)wbf;              // 52 chunks x [2 kh][256 n] pieces
  const int nA = w * 32 + l31;                        // wave's 32-col slice
  const int pOff = lh * 256 + nA;                     // piece offset within chunk

  short8 pa[4];
#pragma unroll
  for (int i = 0; i < 4; ++i) pa[i] = Wt[i * 512 + pOff];

  // phase 0: h0 = relu(pre_j[b,j] + pre_i[b,i] + pre_q[b]) -> buffer 0
  {
    int r = tid & 63, kc = tid >> 6;
    const float* pj = pre_j + (b * 64 + j) * GS;
    const float* pi = pre_i + (b * 64 + r) * GS;
    const float* pq = pre_q + b * GS;
    int rowbase = r * 512;
    int sw = (r & 31) << 4;
#pragma unroll
    for (int kk = 0; kk < 4; ++kk) {
      int n0 = kc * 32 + kk * 8;
      float4 va  = *(const float4*)(pi + n0);
      float4 va2 = *(const float4*)(pi + n0 + 4);
      float4 vj  = *(const float4*)(pj + n0);
      float4 vj2 = *(const float4*)(pj + n0 + 4);
      float4 vq  = *(const float4*)(pq + n0);
      float4 vq2 = *(const float4*)(pq + n0 + 4);
      short8 pack;
      pack[0] = (short)f2bf(fmaxf(va.x  + vj.x  + vq.x,  0.0f));
      pack[1] = (short)f2bf(fmaxf(va.y  + vj.y  + vq.y,  0.0f));
      pack[2] = (short)f2bf(fmaxf(va.z  + vj.z  + vq.z,  0.0f));
      pack[3] = (short)f2bf(fmaxf(va.w  + vj.w  + vq.w,  0.0f));
      pack[4] = (short)f2bf(fmaxf(va2.x + vj2.x + vq2.x, 0.0f));
      pack[5] = (short)f2bf(fmaxf(va2.y + vj2.y + vq2.y, 0.0f));
      pack[6] = (short)f2bf(fmaxf(va2.z + vj2.z + vq2.z, 0.0f));
      pack[7] = (short)f2bf(fmaxf(va2.w + vj2.w + vq2.w, 0.0f));
      *(short8*)(hb + rowbase + ((n0 * 2) ^ sw)) = pack;
    }
  }
  asm volatile("s_waitcnt lgkmcnt(0)" ::: "memory");
  __builtin_amdgcn_s_barrier();
  __builtin_amdgcn_sched_barrier(0);

  const int rA0 = l31 * 512;
  const int rA1 = (32 + l31) * 512;
  const int swA = l31 << 4;

#pragma unroll 1
  for (int L = 0; L < 3; ++L) {
    char* rb = hb + (L & 1) * 32768;                  // read buffer (h(L))
    char* wbuf = hb + ((L + 1) & 1) * 32768;          // write buffer (h(L+1) / colsum)
    const float* bias = (L == 0) ? g2b : ((L == 1) ? g3b : g4b);
    float biasA = bias[nA];
    f32x16 acc0 = {}, acc1 = {};
    short8 a0[2], a1[2];
#pragma unroll
    for (int i = 0; i < 2; ++i) {
      int colb = (i * 32 + lh * 16) ^ swA;
      a0[i] = *(const short8*)(rb + rA0 + colb);
      a1[i] = *(const short8*)(rb + rA1 + colb);
    }
#pragma unroll
    for (int kt = 0; kt < 16; ++kt) {
      short8 nb = Wt[(L * 16 + kt + 4) * 512 + pOff];
      acc0 = __builtin_amdgcn_mfma_f32_32x32x16_bf16(a0[kt & 1], pa[kt & 3], acc0, 0, 0, 0);
      acc1 = __builtin_amdgcn_mfma_f32_32x32x16_bf16(a1[kt & 1], pa[kt & 3], acc1, 0, 0, 0);
      int ktn = (kt < 14) ? kt + 2 : 15;
      int colb = (ktn * 32 + lh * 16) ^ swA;
      a0[kt & 1] = *(const short8*)(rb + rA0 + colb);
      a1[kt & 1] = *(const short8*)(rb + rA1 + colb);
      pa[kt & 3] = nb;
    }
    // NO reads-done barrier: epilogue writes the OTHER buffer.
    if (L < 2) {
#pragma unroll
      for (int reg = 0; reg < 16; ++reg) {
        int rr = (reg & 3) + 8 * (reg >> 2) + 4 * lh; // 0..31
        int swr = rr << 4;
        unsigned short v0 = f2bf(fmaxf(acc0[reg] + biasA, 0.0f));
        unsigned short v1 = f2bf(fmaxf(acc1[reg] + biasA, 0.0f));
        *(unsigned short*)(wbuf + rr * 512        + ((nA * 2) ^ swr)) = v0;
        *(unsigned short*)(wbuf + (32 + rr) * 512 + ((nA * 2) ^ swr)) = v1;
      }
      asm volatile("s_waitcnt lgkmcnt(0)" ::: "memory");
      __builtin_amdgcn_s_barrier();                   // h(L+1) visible
      __builtin_amdgcn_sched_barrier(0);
    } else {
      float sA = 0.0f;
#pragma unroll
      for (int reg = 0; reg < 16; ++reg)
        sA += fmaxf(acc0[reg] + biasA, 0.0f) + fmaxf(acc1[reg] + biasA, 0.0f);
      sA += __shfl_xor(sA, 32);
      float* fs = (float*)wbuf;                       // buf1: dead data, safe
      if (lh == 0) fs[nA] = sA;
      asm volatile("s_waitcnt lgkmcnt(0)" ::: "memory");
      __builtin_amdgcn_s_barrier();
      __builtin_amdgcn_sched_barrier(0);
      if (tid < GS) xpart[bid * GS + tid] = fs[tid];
    }
  }
}

// ---------------- final: reduce xpart over j + f-MLP + log_softmax ----------------
__global__ __launch_bounds__(256) void final_k(const float* __restrict__ xpart,
                                               const float* __restrict__ f1w,
                                               const float* __restrict__ f1b,
                                               const float* __restrict__ f2w,
                                               const float* __restrict__ f2b,
                                               const float* __restrict__ f3w,
                                               const float* __restrict__ f3b,
                                               float* __restrict__ out) {
  int b = blockIdx.x, n = threadIdx.x;
  __shared__ float s0[GS], s1[GS], sl[16];
  float xs = 0.0f;
  for (int j = 0; j < 64; ++j) xs += xpart[(b * 64 + j) * GS + n];
  s0[n] = xs;
  __syncthreads();
  float a = f1b[n];
  {
    const float4* wr = (const float4*)(f1w + n * GS);
    for (int k = 0; k < GS / 4; ++k) {
      float4 wv = wr[k];
      a += wv.x * s0[k * 4] + wv.y * s0[k * 4 + 1] + wv.z * s0[k * 4 + 2] + wv.w * s0[k * 4 + 3];
    }
  }
  s1[n] = fmaxf(a, 0.0f);
  __syncthreads();
  a = f2b[n];
  {
    const float4* wr = (const float4*)(f2w + n * GS);
    for (int k = 0; k < GS / 4; ++k) {
      float4 wv = wr[k];
      a += wv.x * s1[k * 4] + wv.y * s1[k * 4 + 1] + wv.z * s1[k * 4 + 2] + wv.w * s1[k * 4 + 3];
    }
  }
  s0[n] = fmaxf(a, 0.0f);
  __syncthreads();
  if (n < ANSS) {
    a = f3b[n];
    const float4* wr = (const float4*)(f3w + n * GS);
    for (int k = 0; k < GS / 4; ++k) {
      float4 wv = wr[k];
      a += wv.x * s0[k * 4] + wv.y * s0[k * 4 + 1] + wv.z * s0[k * 4 + 2] + wv.w * s0[k * 4 + 3];
    }
    sl[n] = a;
  }
  __syncthreads();
  if (n == 0) {
    float m = -1e30f;
    for (int i = 0; i < ANSS; ++i) m = fmaxf(m, sl[i]);
    float s = 0.0f;
    for (int i = 0; i < ANSS; ++i) s += expf(sl[i] - m);
    sl[12] = m + logf(s);
  }
  __syncthreads();
  if (n < ANSS) out[b * ANSS + n] = sl[n] - sl[12];
}

extern "C" void kernel_launch(void* const* d_in, const int* in_sizes, int n_in,
                              void* d_out, int out_size, void* d_ws, size_t ws_size,
                              hipStream_t stream) {
  const float* image = (const float*)d_in[0];
  const int*   question = (const int*)d_in[1];
  const float* emb = (const float*)d_in[2];
  const float* wih = (const float*)d_in[3];
  const float* whh = (const float*)d_in[4];
  const float* bih = (const float*)d_in[5];
  const float* bhh = (const float*)d_in[6];
  const float* c1w = (const float*)d_in[7];
  const float* c1b = (const float*)d_in[8];
  const float* bn1g = (const float*)d_in[9];
  const float* bn1b = (const float*)d_in[10];
  const float* c2w = (const float*)d_in[11];
  const float* c2b = (const float*)d_in[12];
  const float* bn2g = (const float*)d_in[13];
  const float* bn2b = (const float*)d_in[14];
  const float* c3w = (const float*)d_in[15];
  const float* c3b = (const float*)d_in[16];
  const float* bn3g = (const float*)d_in[17];
  const float* bn3b = (const float*)d_in[18];
  const float* c4w = (const float*)d_in[19];
  const float* c4b = (const float*)d_in[20];
  const float* bn4g = (const float*)d_in[21];
  const float* bn4b = (const float*)d_in[22];
  const float* g1w = (const float*)d_in[23];
  const float* g1b = (const float*)d_in[24];
  const float* g2w = (const float*)d_in[25];
  const float* g2b = (const float*)d_in[26];
  const float* g3w = (const float*)d_in[27];
  const float* g3b = (const float*)d_in[28];
  const float* g4w = (const float*)d_in[29];
  const float* g4b = (const float*)d_in[30];
  const float* f1w = (const float*)d_in[31];
  const float* f1b = (const float*)d_in[32];
  const float* f2w = (const float*)d_in[33];
  const float* f2b = (const float*)d_in[34];
  const float* f3w = (const float*)d_in[35];
  const float* f3b = (const float*)d_in[36];
  float* out = (float*)d_out;

  float* wsf = (float*)d_ws;
  float* arenaA = wsf;                                // 6,291,456 f (y1/y3; later xpart)
  float* arenaB = wsf + 6291456;                      // 1,572,864 f (y2/y4)
  float* qvec   = wsf + 8519680;                      // 8,192 f
  float* pre_i  = wsf + 8527872;                      // 1,048,576 f
  float* pre_j  = wsf + 9576448;                      // 1,048,576 f
  float* pre_q  = wsf + 10625024;                     // 16,384 f
  float* stats  = wsf + 10657792;                     // 3,072 f (4 layers x 16 bkt x 24 x 2)
  unsigned short* wbf = (unsigned short*)(wsf + 10660864); // 52 chunks = 212,992 bf16
  float* g1wT   = wsf + 10767360;                     // 46,080 f
  float* xpart  = arenaA;                             // reuse: convs done before rel_k

  head_k<<<538, 512, 0, stream>>>(g2w, g3w, g4w, wbf, g1w, g1wT, stats,
                                  question, emb, wih, bih, bhh, whh, qvec);

  conv_k<3, 128, false><<<3072, 256, 0, stream>>>(image, c1w, c1b, arenaA,
                                                  nullptr, nullptr, nullptr, 0.0f,
                                                  stats + 0);
  conv_k<24, 64, true><<<768, 256, 0, stream>>>(arenaA, c2w, c2b, arenaB,
                                                stats + 0, bn1g, bn1b, 1.0f / 262144.0f,
                                                stats + 768);
  conv_k<24, 32, true><<<192, 256, 0, stream>>>(arenaB, c3w, c3b, arenaA,
                                                stats + 768, bn2g, bn2b, 1.0f / 65536.0f,
                                                stats + 1536);
  conv_k<24, 16, true><<<48, 256, 0, stream>>>(arenaA, c4w, c4b, arenaB,
                                               stats + 1536, bn3g, bn3b, 1.0f / 16384.0f,
                                               stats + 2304);

  pre_k<<<4096 + 64, 256, 0, stream>>>(arenaB, stats + 2304, bn4g, bn4b, g1wT, g1b, qvec,
                                       pre_i, pre_j, pre_q);

  rel_k<<<4096, 512, 0, stream>>>(pre_i, pre_j, pre_q, wbf, g2b, g3b, g4b, xpart);

  final_k<<<64, 256, 0, stream>>>(xpart, f1w, f1b, f2w, f2b, f3w, f3b, out);
}